// Round 1
// baseline (2554.304 us; speedup 1.0000x reference)
//
#include <hip/hip_runtime.h>
#include <cstdint>
#include <cstddef>

// Problem constants
#define B_SZ 512
#define S_SZ 120
#define D_SZ 216
#define H_SZ 1024
#define NG   4096     // 4*H
#define DP   256      // D padded to multiple of BK
#define KENC 1280     // DP + H
#define TMAX 24

// GEMM tile config
#define BM 64
#define BN 128
#define BK 64

using bf16_t = __bf16;
using bf16x8 = __attribute__((ext_vector_type(8))) __bf16;
using f32x4  = __attribute__((ext_vector_type(4))) float;

__device__ __forceinline__ void gload16(const void* g, void* l) {
  __builtin_amdgcn_global_load_lds(
      (const __attribute__((address_space(1))) void*)g,
      (__attribute__((address_space(3))) void*)l, 16, 0, 0);
}
// Coherent variant for h (cross-XCD producer): sc0|sc1 = 0x11 bypasses
// potentially-stale L1/L2 and reads from the device coherence point.
__device__ __forceinline__ void gload16c(const void* g, void* l) {
  __builtin_amdgcn_global_load_lds(
      (const __attribute__((address_space(1))) void*)g,
      (__attribute__((address_space(3))) void*)l, 16, 0, 0x11);
}

__device__ __forceinline__ float fsigmoid(float x) {
  x = fminf(fmaxf(x, -30.f), 30.f);
  return 1.f / (1.f + __expf(-x));
}
__device__ __forceinline__ float ftanh(float x) {
  x = fminf(fmaxf(x, -15.f), 15.f);
  float e = __expf(2.f * x);
  return (e - 1.f) / (e + 1.f);
}

// LDS: THREE staging buffers (A 64x64 bf16 = 8KB + B 128x64 bf16 = 16KB each),
// gate restage union. Tiles stored [row][64] with XOR chunk swizzle applied on
// the GLOBAL fetch side: LDS slot (r, c) holds global 8-elem chunk c^(r&7).
#define BUFB 24576
struct __align__(16) Smem {
  union {
    bf16_t stage[3][(BM + BN) * BK];  // 73728 B
    float gate[BM * 129];             // 33024 B
  };
};

// ---------------------------------------------------------------------------
// Persistent kernel: all 144 LSTM steps in one cooperative launch.
// grid = 256 WGs (1 per CU), 256 threads. Same tile mapping as the old
// per-step launch: n-block = bid&31, m-block = bid>>5 (so bid%8 == n%8 keeps
// the same-B-panel blocks on one XCD -> W panels are L2-resident across ALL
// steps, since we never flush/invalidate L2 inside the kernel).
// Cross-XCD coherence is handled ONLY on h: sc0|sc1 stores (straight to the
// coherence point) + sc0|sc1 staged loads. Grid barrier is a relaxed
// monotonic counter: ordering comes from the vmcnt(0) drain at __syncthreads
// before arrival (sc1 store acks == globally visible).
// ---------------------------------------------------------------------------
__global__ __launch_bounds__(256, 1) void lstm_chain(
    const bf16_t* __restrict__ srcbf,
    const bf16_t* __restrict__ Wcat,
    const bf16_t* __restrict__ Wdec,
    const float* __restrict__ biasE,
    const float* __restrict__ biasD,
    float* __restrict__ cbuf,
    bf16_t* __restrict__ hA,
    bf16_t* __restrict__ hB,
    bf16_t* __restrict__ Hs,
    unsigned* __restrict__ bar)
{
  __shared__ Smem sm;
  const int t    = threadIdx.x;
  const int bid  = blockIdx.x;
  const int n0   = (bid & 31) * BN;   // matches old dim3(32,8) x-fastest order
  const int m0   = (bid >> 5) * BM;
  const int lane = t & 63;
  const int wv   = t >> 6;
  const int wm   = wv >> 1, wn = wv & 1;
  const int fr   = lane & 15;
  const int fq   = lane >> 4;

  const int r0   = t >> 3;
  const int gcol = (((t & 7) ^ (r0 & 7)) * 8);
  char* ldsbase  = (char*)&sm.stage[0][0];
  const int wofs = wv * 1024;

  const int swz  = fr & 7;
  const int co0  = ((fq) ^ swz) * 16;
  const int co1  = ((4 + fq) ^ swz) * 16;
  const int arow0 = (wm * 32 + fr) * 128;
  const int arow1 = (wm * 32 + 16 + fr) * 128;
  const int brow  = (wn * 64 + fr) * 128;
  const int u0    = n0 >> 2;

  const bf16_t* hprev = hA;
  unsigned target = 0;

#pragma clang loop unroll(disable)
  for (int s = 0; s < 144; ++s) {
    const bool enc = (s <= 120);
    const int  xi  = (s < 120) ? s : 119;
    const bf16_t* A1  = enc ? (srcbf + (size_t)xi * B_SZ * DP) : hprev;
    const int     sA1 = enc ? DP : H_SZ;
    const int     n1  = enc ? (DP / BK) : 0;
    const bf16_t* W   = enc ? Wcat : Wdec;
    const int     sW  = enc ? KENC : H_SZ;
    const float*  bias = enc ? biasE : biasD;
    bf16_t* hnext = (s < 120) ? ((s & 1) ? hA : hB)
                              : (Hs + (size_t)(s - 120) * B_SZ * H_SZ);
    const int nTot = n1 + H_SZ / BK;   // 20 encoder, 16 decoder

    float bias4[4];
#pragma unroll
    for (int j = 0; j < 4; ++j) bias4[j] = bias[n0 + wn * 64 + j * 16 + fr];

    const bf16_t* a1p0 = A1 + (size_t)(m0 + r0) * sA1 + gcol;
    const bf16_t* a1p1 = A1 + (size_t)(m0 + r0 + 32) * sA1 + gcol;
    const bf16_t* a2p0 = hprev + (size_t)(m0 + r0) * H_SZ + gcol;
    const bf16_t* a2p1 = hprev + (size_t)(m0 + r0 + 32) * H_SZ + gcol;
    const bf16_t* wp0  = W + (size_t)(n0 + r0) * sW + gcol;
    const bf16_t* wp1  = W + (size_t)(n0 + r0 + 32) * sW + gcol;
    const bf16_t* wp2  = W + (size_t)(n0 + r0 + 64) * sW + gcol;
    const bf16_t* wp3  = W + (size_t)(n0 + r0 + 96) * sW + gcol;

    f32x4 acc[2][4] = {};

    auto stage = [&](int j, int bf) {
      char* Ab = ldsbase + bf * BUFB + wofs;
      char* Bb = ldsbase + bf * BUFB + 8192 + wofs;
      const int k = j * BK;
      if (j < n1) {                       // src part: plain cached loads
        gload16(a1p0 + k, Ab);
        gload16(a1p1 + k, Ab + 4096);
      } else {                            // h part: coherent bypass loads
        const int k2 = k - n1 * BK;
        gload16c(a2p0 + k2, Ab);
        gload16c(a2p1 + k2, Ab + 4096);
      }
      gload16(wp0 + k, Bb);
      gload16(wp1 + k, Bb + 4096);
      gload16(wp2 + k, Bb + 8192);
      gload16(wp3 + k, Bb + 12288);
    };

    auto compute = [&](int bf) {
      const char* Ab = ldsbase + bf * BUFB;
      const char* Bb = Ab + 8192;
#pragma unroll
      for (int kk = 0; kk < 2; ++kk) {
        const int co = kk ? co1 : co0;
        bf16x8 av0 = *(const bf16x8*)(Ab + arow0 + co);
        bf16x8 av1 = *(const bf16x8*)(Ab + arow1 + co);
        bf16x8 bv[4];
#pragma unroll
        for (int j = 0; j < 4; ++j)
          bv[j] = *(const bf16x8*)(Bb + brow + j * 2048 + co);
#pragma unroll
        for (int j = 0; j < 4; ++j) {
          acc[0][j] = __builtin_amdgcn_mfma_f32_16x16x32_bf16(av0, bv[j], acc[0][j], 0, 0, 0);
          acc[1][j] = __builtin_amdgcn_mfma_f32_16x16x32_bf16(av1, bv[j], acc[1][j], 0, 0, 0);
        }
      }
    };

    // 3-buffer pipelined K-loop, depth-2 prefetch, vmcnt(6) steady-state.
    stage(0, 0);
    stage(1, 1);
    int cb = 0, sb = 2;
    for (int it = 0; it < nTot; ++it) {
      if (it == nTot - 1) {
        asm volatile("s_waitcnt vmcnt(0)" ::: "memory");
      } else {
        asm volatile("s_waitcnt vmcnt(6)" ::: "memory");
      }
      __builtin_amdgcn_s_barrier();
      if (it + 2 < nTot) stage(it + 2, sb);
      sb = (sb == 2) ? 0 : sb + 1;
      compute(cb);
      cb = (cb == 2) ? 0 : cb + 1;
    }
    __syncthreads();  // before gate-restage union reuse

    // ---- LSTM cell epilogue (identical math to the per-step kernel) ----
#pragma unroll
    for (int i = 0; i < 2; ++i)
#pragma unroll
      for (int j = 0; j < 4; ++j)
#pragma unroll
        for (int v = 0; v < 4; ++v) {
          int row = wm * 32 + i * 16 + fq * 4 + v;
          int col = wn * 64 + j * 16 + fr;
          sm.gate[row * 129 + col] = acc[i][j][v] + bias4[j];
        }
    __syncthreads();
#pragma unroll
    for (int itc = 0; itc < 8; ++itc) {
      int ci  = itc * 256 + t;
      int brw = ci >> 5;
      int ju  = ci & 31;
      const float* gp = &sm.gate[brw * 129 + ju * 4];
      float iv = fsigmoid(gp[0]);
      float fv = fsigmoid(gp[1]);
      float gv = ftanh(gp[2]);
      float ov = fsigmoid(gp[3]);
      size_t cix = (size_t)(m0 + brw) * H_SZ + (u0 + ju);
      float cn = fv * cbuf[cix] + iv * gv;     // cbuf is WG-private: plain path
      cbuf[cix] = cn;
      bf16_t hb = (bf16_t)(ov * ftanh(cn));
      // h crosses XCDs next step: store straight to the coherence point.
      uint32_t hv32 = (uint32_t)__builtin_bit_cast(uint16_t, hb);
      asm volatile("global_store_short %0, %1, off sc0 sc1"
                   :: "v"((uint16_t*)&hnext[cix]), "v"(hv32) : "memory");
    }

    // ---- relaxed grid barrier (monotonic counter; no L2 flush/inv) ----
    // __syncthreads drains vmcnt(0): all sc1 h-stores are MALL-visible
    // before our arrival increment can be observed.
    target += 256;
    __syncthreads();
    if (t == 0) {
      __hip_atomic_fetch_add(bar, 1u, __ATOMIC_RELAXED, __HIP_MEMORY_SCOPE_AGENT);
      while (__hip_atomic_load(bar, __ATOMIC_RELAXED, __HIP_MEMORY_SCOPE_AGENT) < target)
        __builtin_amdgcn_s_sleep(2);
    }
    __syncthreads();

    hprev = hnext;
  }
}

// ---------------------------------------------------------------------------
// Standalone GEMM (kept for EPI=2 W_dec build and EPI=3 final projection)
// ---------------------------------------------------------------------------
template <int EPI>
__global__ __launch_bounds__(256, 1) void gemm_step(
    const bf16_t* __restrict__ A1, int sA1, int n1,
    const bf16_t* __restrict__ A2, int sA2, int n2,
    const bf16_t* __restrict__ W, int sW,
    const float* __restrict__ bias,
    float* __restrict__ cbuf, bf16_t* __restrict__ hout,
    const float* __restrict__ addm, bf16_t* __restrict__ outb,
    float* __restrict__ outf)
{
  __shared__ Smem sm;
  const int t    = threadIdx.x;
  const int m0   = blockIdx.y * BM;
  const int n0   = blockIdx.x * BN;
  const int lane = t & 63;
  const int wv   = t >> 6;
  const int wm   = wv >> 1, wn = wv & 1;
  const int fr   = lane & 15;
  const int fq   = lane >> 4;

  f32x4 acc[2][4] = {};

  float bias4[4];
  if (EPI == 1 || EPI == 3) {
#pragma unroll
    for (int j = 0; j < 4; ++j) {
      int col = n0 + wn * 64 + j * 16 + fr;
      bias4[j] = (EPI == 3 && col >= D_SZ) ? 0.f : bias[col];
    }
  }

  const int r0   = t >> 3;
  const int gcol = (((t & 7) ^ (r0 & 7)) * 8);
  char* ldsbase  = (char*)&sm.stage[0][0];
  const int wofs = wv * 1024;

  const bf16_t* pA1 = A1 ? A1 : A2;
  const bf16_t* pA2 = A2 ? A2 : A1;
  const bf16_t* a1p0 = pA1 + (size_t)(m0 + r0) * sA1 + gcol;
  const bf16_t* a1p1 = pA1 + (size_t)(m0 + r0 + 32) * sA1 + gcol;
  const bf16_t* a2p0 = pA2 + (size_t)(m0 + r0) * sA2 + gcol;
  const bf16_t* a2p1 = pA2 + (size_t)(m0 + r0 + 32) * sA2 + gcol;
  const bf16_t* wp0  = W + (size_t)(n0 + r0) * sW + gcol;
  const bf16_t* wp1  = W + (size_t)(n0 + r0 + 32) * sW + gcol;
  const bf16_t* wp2  = W + (size_t)(n0 + r0 + 64) * sW + gcol;
  const bf16_t* wp3  = W + (size_t)(n0 + r0 + 96) * sW + gcol;

  const int nTot = n1 + n2;

  auto stage = [&](int j, int bf) {
    char* Ab = ldsbase + bf * BUFB + wofs;
    char* Bb = ldsbase + bf * BUFB + 8192 + wofs;
    const int k = j * BK;
    const bf16_t *a0, *a1;
    if (j < n1) { a0 = a1p0 + k; a1 = a1p1 + k; }
    else { const int k2 = k - n1 * BK; a0 = a2p0 + k2; a1 = a2p1 + k2; }
    gload16(a0, Ab);
    gload16(a1, Ab + 4096);
    gload16(wp0 + k, Bb);
    gload16(wp1 + k, Bb + 4096);
    gload16(wp2 + k, Bb + 8192);
    gload16(wp3 + k, Bb + 12288);
  };

  const int swz  = fr & 7;
  const int co0  = ((fq) ^ swz) * 16;
  const int co1  = ((4 + fq) ^ swz) * 16;
  const int arow0 = (wm * 32 + fr) * 128;
  const int arow1 = (wm * 32 + 16 + fr) * 128;
  const int brow  = (wn * 64 + fr) * 128;

  auto compute = [&](int bf) {
    const char* Ab = ldsbase + bf * BUFB;
    const char* Bb = Ab + 8192;
#pragma unroll
    for (int kk = 0; kk < 2; ++kk) {
      const int co = kk ? co1 : co0;
      bf16x8 av0 = *(const bf16x8*)(Ab + arow0 + co);
      bf16x8 av1 = *(const bf16x8*)(Ab + arow1 + co);
      bf16x8 bv[4];
#pragma unroll
      for (int j = 0; j < 4; ++j)
        bv[j] = *(const bf16x8*)(Bb + brow + j * 2048 + co);
#pragma unroll
      for (int j = 0; j < 4; ++j) {
        acc[0][j] = __builtin_amdgcn_mfma_f32_16x16x32_bf16(av0, bv[j], acc[0][j], 0, 0, 0);
        acc[1][j] = __builtin_amdgcn_mfma_f32_16x16x32_bf16(av1, bv[j], acc[1][j], 0, 0, 0);
      }
    }
  };

  stage(0, 0);
  if (nTot > 1) stage(1, 1);
  int cb = 0, sb = 2;
  for (int it = 0; it < nTot; ++it) {
    if (it == nTot - 1) {
      asm volatile("s_waitcnt vmcnt(0)" ::: "memory");
    } else {
      asm volatile("s_waitcnt vmcnt(6)" ::: "memory");
    }
    __builtin_amdgcn_s_barrier();
    if (it + 2 < nTot) stage(it + 2, sb);
    sb = (sb == 2) ? 0 : sb + 1;
    compute(cb);
    cb = (cb == 2) ? 0 : cb + 1;
  }
  __syncthreads();

  if (EPI == 1) {
#pragma unroll
    for (int i = 0; i < 2; ++i)
#pragma unroll
      for (int j = 0; j < 4; ++j)
#pragma unroll
        for (int v = 0; v < 4; ++v) {
          int row = wm * 32 + i * 16 + fq * 4 + v;
          int col = wn * 64 + j * 16 + fr;
          sm.gate[row * 129 + col] = acc[i][j][v] + bias4[j];
        }
    __syncthreads();
    const int u0 = n0 >> 2;
#pragma unroll
    for (int itc = 0; itc < 8; ++itc) {
      int ci = itc * 256 + t;
      int brw = ci >> 5;
      int ju  = ci & 31;
      const float* gp = &sm.gate[brw * 129 + ju * 4];
      float iv = fsigmoid(gp[0]);
      float fv = fsigmoid(gp[1]);
      float gv = ftanh(gp[2]);
      float ov = fsigmoid(gp[3]);
      size_t cix = (size_t)(m0 + brw) * H_SZ + (u0 + ju);
      float cn = fv * cbuf[cix] + iv * gv;
      cbuf[cix] = cn;
      hout[cix] = (bf16_t)(ov * ftanh(cn));
    }
  }

  if (EPI == 2) {
#pragma unroll
    for (int i = 0; i < 2; ++i)
#pragma unroll
      for (int j = 0; j < 4; ++j)
#pragma unroll
        for (int v = 0; v < 4; ++v) {
          int gr = m0 + wm * 32 + i * 16 + fq * 4 + v;
          int gc = n0 + wn * 64 + j * 16 + fr;
          int orig = (gr & 3) * H_SZ + (gr >> 2);
          float val = acc[i][j][v] + addm[(size_t)orig * H_SZ + gc];
          outb[(size_t)gr * H_SZ + gc] = (bf16_t)val;
        }
  }

  if (EPI == 3) {
#pragma unroll
    for (int i = 0; i < 2; ++i)
#pragma unroll
      for (int j = 0; j < 4; ++j)
#pragma unroll
        for (int v = 0; v < 4; ++v) {
          int m = m0 + wm * 32 + i * 16 + fq * 4 + v;
          int n = n0 + wn * 64 + j * 16 + fr;
          if (n < D_SZ) {
            int ts = m >> 9;
            int bb = m & 511;
            outf[((size_t)bb * TMAX + ts) * D_SZ + n] = acc[i][j][v] + bias4[j];
          }
        }
  }
}

// src (B,S,D) fp32 -> srcbf (S,B,DP) bf16, zero-padded d>=216
__global__ void k_convert_src(const float* __restrict__ src, bf16_t* __restrict__ dst) {
  int idx = blockIdx.x * 256 + threadIdx.x;
  int total = S_SZ * B_SZ * DP;
  if (idx >= total) return;
  int d = idx % DP;
  int r = idx / DP;
  int b = r % B_SZ;
  int tt = r / B_SZ;
  float v = (d < D_SZ) ? src[((size_t)b * S_SZ + tt) * D_SZ + d] : 0.f;
  dst[idx] = (bf16_t)v;
}

__global__ void k_build_wcat(const float* __restrict__ Wih, const float* __restrict__ Whh,
                             bf16_t* __restrict__ Wcat) {
  int idx = blockIdx.x * 256 + threadIdx.x;
  if (idx >= NG * KENC) return;
  int k = idx % KENC;
  int r = idx / KENC;
  int o = (r & 3) * H_SZ + (r >> 2);
  float v;
  if (k < D_SZ)      v = Wih[(size_t)o * D_SZ + k];
  else if (k < DP)   v = 0.f;
  else               v = Whh[(size_t)o * H_SZ + (k - DP)];
  Wcat[idx] = (bf16_t)v;
}

__global__ void k_build_wout(const float* __restrict__ Wout, bf16_t* __restrict__ WoutB,
                             bf16_t* __restrict__ WoutT) {
  int idx = blockIdx.x * 256 + threadIdx.x;
  if (idx < 256 * H_SZ) {
    int h = idx % H_SZ, d = idx / H_SZ;
    WoutB[idx] = (bf16_t)((d < D_SZ) ? Wout[(size_t)d * H_SZ + h] : 0.f);
  }
  if (idx < H_SZ * DP) {
    int d = idx % DP, h = idx / DP;
    WoutT[idx] = (bf16_t)((d < D_SZ) ? Wout[(size_t)d * H_SZ + h] : 0.f);
  }
}

__global__ void k_build_bias(const float* __restrict__ bih, const float* __restrict__ bhh,
                             const float* __restrict__ Wih, const float* __restrict__ bout,
                             float* __restrict__ biasE, float* __restrict__ biasD) {
  int r = blockIdx.x * 256 + threadIdx.x;
  if (r >= NG) return;
  int o = (r & 3) * H_SZ + (r >> 2);
  float be = bih[o] + bhh[o];
  biasE[r] = be;
  float s = 0.f;
  const float* wr = Wih + (size_t)o * D_SZ;
  for (int d = 0; d < D_SZ; ++d) s += wr[d] * bout[d];
  biasD[r] = be + s;
}

extern "C" void kernel_launch(void* const* d_in, const int* in_sizes, int n_in,
                              void* d_out, int out_size, void* d_ws, size_t ws_size,
                              hipStream_t stream) {
  const float* src  = (const float*)d_in[0];
  const float* Wih  = (const float*)d_in[1];
  const float* Whh  = (const float*)d_in[2];
  const float* bih  = (const float*)d_in[3];
  const float* bhh  = (const float*)d_in[4];
  const float* Wout = (const float*)d_in[5];
  const float* bout = (const float*)d_in[6];

  char* ws = (char*)d_ws;
  size_t off = 0;
  auto alloc = [&](size_t bytes) {
    void* p = ws + off;
    off = (off + bytes + 255) & ~(size_t)255;
    return p;
  };
  bf16_t* srcbf = (bf16_t*)alloc((size_t)S_SZ * B_SZ * DP * 2);
  bf16_t* Wcat  = (bf16_t*)alloc((size_t)NG * KENC * 2);
  bf16_t* Wdec  = (bf16_t*)alloc((size_t)NG * H_SZ * 2);
  bf16_t* WoutB = (bf16_t*)alloc((size_t)256 * H_SZ * 2);
  bf16_t* WoutT = (bf16_t*)alloc((size_t)H_SZ * DP * 2);
  float*  biasE = (float*)alloc((size_t)NG * 4);
  float*  biasD = (float*)alloc((size_t)NG * 4);
  float*  cbuf  = (float*)alloc((size_t)B_SZ * H_SZ * 4);
  bf16_t* hP0   = (bf16_t*)alloc((size_t)B_SZ * H_SZ * 2);
  bf16_t* hP1   = (bf16_t*)alloc((size_t)B_SZ * H_SZ * 2);
  bf16_t* Hs    = (bf16_t*)alloc((size_t)TMAX * B_SZ * H_SZ * 2);
  unsigned* bar = (unsigned*)alloc(256);

  hipMemsetAsync(cbuf, 0, (size_t)B_SZ * H_SZ * 4, stream);
  hipMemsetAsync(hP0, 0, (size_t)B_SZ * H_SZ * 2, stream);
  hipMemsetAsync(bar, 0, 256, stream);

  k_convert_src<<<(S_SZ * B_SZ * DP + 255) / 256, 256, 0, stream>>>(src, srcbf);
  k_build_wcat<<<(NG * KENC + 255) / 256, 256, 0, stream>>>(Wih, Whh, Wcat);
  k_build_wout<<<1024, 256, 0, stream>>>(Wout, WoutB, WoutT);
  k_build_bias<<<(NG + 255) / 256, 256, 0, stream>>>(bih, bhh, Wih, bout, biasE, biasD);

  // W_dec = W_hh(reordered) + W_ih(reordered) @ W_out   (M=4096, N=1024, K=256)
  gemm_step<2><<<dim3(H_SZ / BN, NG / BM), 256, 0, stream>>>(
      Wcat, KENC, DP / BK, nullptr, 0, 0, WoutT, DP,
      nullptr, nullptr, nullptr, Whh, Wdec, nullptr);

  // All 144 sequential steps in one persistent cooperative kernel.
  {
    const bf16_t* a_src = srcbf;
    const bf16_t* a_wc  = Wcat;
    const bf16_t* a_wd  = Wdec;
    const float*  a_bE  = biasE;
    const float*  a_bD  = biasD;
    float*        a_cb  = cbuf;
    bf16_t*       a_hA  = hP0;
    bf16_t*       a_hB  = hP1;
    bf16_t*       a_Hs  = Hs;
    unsigned*     a_bar = bar;
    void* kargs[] = {&a_src, &a_wc, &a_wd, &a_bE, &a_bD,
                     &a_cb, &a_hA, &a_hB, &a_Hs, &a_bar};
    hipLaunchCooperativeKernel((void*)lstm_chain, dim3(256), dim3(256),
                               kargs, 0, stream);
  }

  // Final projection: Y(12288 x 216) = Hs(12288 x 1024) @ W_out^T + b_out
  gemm_step<3><<<dim3(2, (TMAX * B_SZ) / BM), 256, 0, stream>>>(
      nullptr, 0, 0, Hs, H_SZ, H_SZ / BK, WoutB, H_SZ,
      bout, nullptr, nullptr, nullptr, nullptr, (float*)d_out);
}

// Round 2
// 2429.651 us; speedup vs baseline: 1.0513x; 1.0513x over previous
//
#include <hip/hip_runtime.h>
#include <cstdint>
#include <cstddef>

// Problem constants
#define B_SZ 512
#define S_SZ 120
#define D_SZ 216
#define H_SZ 1024
#define NG   4096     // 4*H
#define DP   256      // D padded to multiple of BK
#define KENC 1280     // DP + H
#define TMAX 24

// GEMM tile config
#define BM 64
#define BN 128
#define BK 64

using bf16_t = __bf16;
using bf16x8 = __attribute__((ext_vector_type(8))) __bf16;
using f32x4  = __attribute__((ext_vector_type(4))) float;

__device__ __forceinline__ void gload16(const void* g, void* l) {
  __builtin_amdgcn_global_load_lds(
      (const __attribute__((address_space(1))) void*)g,
      (__attribute__((address_space(3))) void*)l, 16, 0, 0);
}
// Coherent variant for h (cross-XCD producer): sc0|sc1 bypasses potentially
// stale L1/L2 and reads from the device coherence point (MALL).
__device__ __forceinline__ void gload16c(const void* g, void* l) {
  __builtin_amdgcn_global_load_lds(
      (const __attribute__((address_space(1))) void*)g,
      (__attribute__((address_space(3))) void*)l, 16, 0, 0x11);
}

__device__ __forceinline__ float fsigmoid(float x) {
  x = fminf(fmaxf(x, -30.f), 30.f);
  return 1.f / (1.f + __expf(-x));
}
__device__ __forceinline__ float ftanh(float x) {
  x = fminf(fmaxf(x, -15.f), 15.f);
  float e = __expf(2.f * x);
  return (e - 1.f) / (e + 1.f);
}

// LDS: THREE staging buffers (A 64x64 bf16 = 8KB + B 128x64 bf16 = 16KB each)
// PLUS a separate gate region (no union!) so cross-step prefetch into the
// staging buffers can proceed while the epilogue uses the gate region.
// Tiles stored [row][64] with XOR chunk swizzle applied on the GLOBAL fetch
// side: LDS slot (r, c) holds global 8-elem chunk c^(r&7).
#define BUFB 24576
struct __align__(16) Smem {
  bf16_t stage[3][(BM + BN) * BK];  // 73728 B
  float gate[BM * 129];             // 33024 B  (total 106752 B < 160 KiB)
};

// ---------------------------------------------------------------------------
// Persistent kernel: all 144 LSTM steps, ONE cooperative launch, NO global
// barrier. Synchronization = 256 per-WG monotonic flags (value = completed
// steps). Dependency is panel-local: consumer k-iter j of step s needs
// h_{s-1} cols [64j,64j+64) = producers nb in {2j,2j+1} of the SAME m-panel,
// so each staging of an h k-slice polls exactly 2 flags (>= s). W staging and
// encoder src-A staging are dependence-free and prefetch ACROSS step
// boundaries (no drain bubble). Wave roles: waves 0/1 stage A (4 chunks each)
// and poll flags; waves 2/3 stage W (8 chunks each, vmcnt(8) steady-state).
// h stores go sc0|sc1 straight to MALL; flag set after per-wave vmcnt(0)
// drain + barrier, so flag-visible => h-visible. Bypass (sc0|sc1) h loads.
// ---------------------------------------------------------------------------
__global__ __launch_bounds__(256, 1) void lstm_chain(
    const bf16_t* __restrict__ srcbf,
    const bf16_t* __restrict__ Wcat,
    const bf16_t* __restrict__ Wdec,
    const float* __restrict__ biasE,
    const float* __restrict__ biasD,
    float* __restrict__ cbuf,
    bf16_t* __restrict__ hA,
    bf16_t* __restrict__ hB,
    bf16_t* __restrict__ Hs,
    unsigned* __restrict__ flags)
{
  __shared__ Smem sm;
  const int t    = threadIdx.x;
  const int bid  = blockIdx.x;
  const int n0   = (bid & 31) * BN;   // x-fastest, same as old dim3(32,8)
  const int m0   = (bid >> 5) * BM;
  const int lane = t & 63;
  const int wv   = t >> 6;
  const int wm   = wv >> 1, wn = wv & 1;
  const int fr   = lane & 15;
  const int fq   = lane >> 4;

  char* ldsbase = (char*)&sm.stage[0][0];

  // ---- staging geometry (wave-specialized) ----
  const int sw8   = (((lane & 7) ^ (lane >> 3)) & 7) * 8;  // swizzled col (elems)
  const int arow  = (wv & 1) * 32 + (lane >> 3);           // waves 0/1: A row
  const int wrow  = (wv & 1) * 64 + (lane >> 3);           // waves 2/3: W row
  const int aldso = (wv & 1) * 4096;
  const int wldso = 8192 + (wv & 1) * 8192;

  // ---- fragment read offsets (swizzle-aware, conflict-free) ----
  const int swz   = fr & 7;
  const int co0   = ((fq) ^ swz) * 16;
  const int co1   = ((4 + fq) ^ swz) * 16;
  const int arow0 = (wm * 32 + fr) * 128;
  const int arow1 = (wm * 32 + 16 + fr) * 128;
  const int brow  = (wn * 64 + fr) * 128;
  const int u0    = n0 >> 2;

  const int panel = m0 >> 6;
  unsigned* flg = flags + panel * 32;   // this panel's 32 producer flags
  unsigned* myf = flg + (n0 >> 7);      // our own flag (BN=128)

  auto stageA = [&](const bf16_t* base, int stride, int kelem, int buf, bool coh) {
    char* Ab = ldsbase + buf * BUFB + aldso;
    const bf16_t* p = base + (size_t)(m0 + arow) * stride + sw8 + kelem;
#pragma unroll
    for (int q = 0; q < 4; ++q) {
      if (coh) gload16c(p, Ab); else gload16(p, Ab);
      p += (size_t)8 * stride;
      Ab += 1024;
    }
  };
  auto stageW = [&](const bf16_t* Wb, int stride, int kelem, int buf) {
    char* Bb = ldsbase + buf * BUFB + wldso;
    const bf16_t* p = Wb + (size_t)(n0 + wrow) * stride + sw8 + kelem;
#pragma unroll
    for (int q = 0; q < 8; ++q) {
      gload16(p, Bb);
      p += (size_t)8 * stride;
      Bb += 1024;
    }
  };

  f32x4 acc[2][4];

  auto compute = [&](int bf) {
    const char* Ab = ldsbase + bf * BUFB;
    const char* Bb = Ab + 8192;
#pragma unroll
    for (int kk = 0; kk < 2; ++kk) {
      const int co = kk ? co1 : co0;
      bf16x8 av0 = *(const bf16x8*)(Ab + arow0 + co);
      bf16x8 av1 = *(const bf16x8*)(Ab + arow1 + co);
      bf16x8 bv[4];
#pragma unroll
      for (int j = 0; j < 4; ++j)
        bv[j] = *(const bf16x8*)(Bb + brow + j * 2048 + co);
#pragma unroll
      for (int j = 0; j < 4; ++j) {
        acc[0][j] = __builtin_amdgcn_mfma_f32_16x16x32_bf16(av0, bv[j], acc[0][j], 0, 0, 0);
        acc[1][j] = __builtin_amdgcn_mfma_f32_16x16x32_bf16(av1, bv[j], acc[1][j], 0, 0, 0);
      }
    }
  };

  // Spin-wait on a pair of flags (combined load + drain; used where a spin is
  // expected or acceptable). vmcnt is per-wave, so this only drains our own
  // outstanding ops.
  auto pollWait = [&](const unsigned* fp, unsigned need) {
    for (;;) {
      uint64_t pv;
      asm volatile("global_load_dwordx2 %0, %1, off sc0 sc1\n\t"
                   "s_waitcnt vmcnt(0)"
                   : "=v"(pv) : "v"(fp) : "memory");
      if ((unsigned)pv >= need && (unsigned)(pv >> 32) >= need) break;
      __builtin_amdgcn_s_sleep(2);
    }
  };

  const bf16_t* hprev = hA;
  int cb = 0;

  // ---- prologue: stage step-0 iters 0,1 (src A + Wcat W) ----
  if (wv < 2) {
    stageA(srcbf, DP, 0, 0, false);
    stageA(srcbf, DP, BK, 1, false);
    asm volatile("s_waitcnt vmcnt(4)" ::: "memory");   // A(0) complete
  } else {
    stageW(Wcat, KENC, 0, 0);
    stageW(Wcat, KENC, BK, 1);
  }

#pragma clang loop unroll(disable)
  for (int s = 0; s < 144; ++s) {
    const bool enc = (s <= 120);
    const int  xi  = (s < 120) ? s : 119;
    const bf16_t* Asrc = srcbf + (size_t)xi * B_SZ * DP;
    const int n1 = enc ? (DP / BK) : 0;
    const bf16_t* Wb  = enc ? Wcat : Wdec;
    const int     sWb = enc ? KENC : H_SZ;
    const float*  bias = enc ? biasE : biasD;
    bf16_t* hnext = (s < 120) ? ((s & 1) ? hA : hB)
                              : (Hs + (size_t)(s - 120) * B_SZ * H_SZ);
    const int nTot = n1 + H_SZ / BK;   // 20 enc-structured, 16 dec
    const bool nxtEnc = (s + 1 <= 120);
    const bf16_t* nxtW  = nxtEnc ? Wcat : Wdec;
    const int     nxtsW = nxtEnc ? KENC : H_SZ;
    const bf16_t* nxtA  = srcbf + (size_t)((s + 1 < 120) ? (s + 1) : 119) * B_SZ * DP;

    float bias4[4];
#pragma unroll
    for (int j = 0; j < 4; ++j) bias4[j] = bias[n0 + wn * 64 + j * 16 + fr];

#pragma unroll
    for (int i = 0; i < 2; ++i)
#pragma unroll
      for (int j = 0; j < 4; ++j) acc[i][j] = (f32x4){0.f, 0.f, 0.f, 0.f};

    for (int it = 0; it < nTot; ++it) {
      // waves 2/3: W(it) guaranteed done once <=8 newest remain in flight
      if (wv >= 2) asm volatile("s_waitcnt vmcnt(8)" ::: "memory");
      __builtin_amdgcn_s_barrier();

      const int j2 = it + 2;
      int sbuf = cb + 2; if (sbuf >= 3) sbuf -= 3;

      if (wv >= 2) {
        if (j2 < nTot)       stageW(Wb, sWb, j2 * BK, sbuf);
        else if (s < 143)    stageW(nxtW, nxtsW, (j2 - nTot) * BK, sbuf);  // cross-step
      }

      // waves 0/1: issue flag load EARLY (hidden under compute), check after
      uint64_t pv = 0; unsigned need = 0; const unsigned* fp = nullptr;
      bool doPoll = false;
      if (wv < 2 && j2 < nTot && j2 >= n1) {
        fp = flg + 2 * (j2 - n1);
        need = (unsigned)s;
        doPoll = true;
        asm volatile("global_load_dwordx2 %0, %1, off sc0 sc1"
                     : "=v"(pv) : "v"(fp) : "memory");
      }

      compute(cb);

      if (wv < 2) {
        if (doPoll) {
          asm volatile("s_waitcnt vmcnt(0)" : "+v"(pv) :: "memory");
          while (!((unsigned)pv >= need && (unsigned)(pv >> 32) >= need)) {
            __builtin_amdgcn_s_sleep(2);
            asm volatile("global_load_dwordx2 %0, %1, off sc0 sc1\n\t"
                         "s_waitcnt vmcnt(0)"
                         : "=v"(pv) : "v"(fp) : "memory");
          }
        } else {
          asm volatile("s_waitcnt vmcnt(0)" ::: "memory");
        }
        if (j2 < nTot) {
          if (j2 < n1) stageA(Asrc, DP, j2 * BK, sbuf, false);
          else         stageA(hprev, H_SZ, (j2 - n1) * BK, sbuf, true);
        } else if (s < 143 && nxtEnc) {
          stageA(nxtA, DP, (j2 - nTot) * BK, sbuf, false);  // next-step src
        }
        // (decoder-next h staging is deferred past our own flag set)
      }

      cb = (cb == 2) ? 0 : cb + 1;
    }

    // ---- LSTM cell epilogue (gate region disjoint from staging buffers) ----
#pragma unroll
    for (int i = 0; i < 2; ++i)
#pragma unroll
      for (int j = 0; j < 4; ++j)
#pragma unroll
        for (int v = 0; v < 4; ++v) {
          int row = wm * 32 + i * 16 + fq * 4 + v;
          int col = wn * 64 + j * 16 + fr;
          sm.gate[row * 129 + col] = acc[i][j][v] + bias4[j];
        }
    __syncthreads();
#pragma unroll
    for (int itc = 0; itc < 8; ++itc) {
      int ci  = itc * 256 + t;
      int brw = ci >> 5;
      int ju  = ci & 31;
      const float* gp = &sm.gate[brw * 129 + ju * 4];
      float iv = fsigmoid(gp[0]);
      float fv = fsigmoid(gp[1]);
      float gv = ftanh(gp[2]);
      float ov = fsigmoid(gp[3]);
      size_t cix = (size_t)(m0 + brw) * H_SZ + (u0 + ju);
      float cn = fv * cbuf[cix] + iv * gv;   // cbuf is WG-private: plain path
      cbuf[cix] = cn;
      bf16_t hb = (bf16_t)(ov * ftanh(cn));
      uint32_t hv32 = (uint32_t)__builtin_bit_cast(uint16_t, hb);
      asm volatile("global_store_short %0, %1, off sc0 sc1"
                   :: "v"((uint16_t*)&hnext[cix]), "v"(hv32) : "memory");
    }
    // per-wave store drain, then barrier, then publish our flag:
    // flag visible at MALL => our h slice visible at MALL.
    asm volatile("s_waitcnt vmcnt(0)" ::: "memory");
    __syncthreads();
    if (t == 0) {
      unsigned fv2 = (unsigned)(s + 1);
      asm volatile("global_store_dword %0, %1, off sc0 sc1"
                   :: "v"(myf), "v"(fv2) : "memory");
    }

    // deferred h staging for decoder-structured next step (iters 0,1 are h)
    if (s < 143 && !nxtEnc && wv < 2) {
      pollWait(flg + 0, (unsigned)(s + 1));
      stageA(hnext, H_SZ, 0, cb, true);
      pollWait(flg + 2, (unsigned)(s + 1));   // also drains the stage above
      stageA(hnext, H_SZ, BK, (cb == 2) ? 0 : cb + 1, true);
    }

    hprev = hnext;
  }
}

// ---------------------------------------------------------------------------
// Standalone GEMM (EPI=2 W_dec build, EPI=3 final projection)
// ---------------------------------------------------------------------------
template <int EPI>
__global__ __launch_bounds__(256, 1) void gemm_step(
    const bf16_t* __restrict__ A1, int sA1, int n1,
    const bf16_t* __restrict__ A2, int sA2, int n2,
    const bf16_t* __restrict__ W, int sW,
    const float* __restrict__ bias,
    float* __restrict__ cbuf, bf16_t* __restrict__ hout,
    const float* __restrict__ addm, bf16_t* __restrict__ outb,
    float* __restrict__ outf)
{
  __shared__ Smem sm;
  const int t    = threadIdx.x;
  const int m0   = blockIdx.y * BM;
  const int n0   = blockIdx.x * BN;
  const int lane = t & 63;
  const int wv   = t >> 6;
  const int wm   = wv >> 1, wn = wv & 1;
  const int fr   = lane & 15;
  const int fq   = lane >> 4;

  f32x4 acc[2][4] = {};

  float bias4[4];
  if (EPI == 1 || EPI == 3) {
#pragma unroll
    for (int j = 0; j < 4; ++j) {
      int col = n0 + wn * 64 + j * 16 + fr;
      bias4[j] = (EPI == 3 && col >= D_SZ) ? 0.f : bias[col];
    }
  }

  const int r0   = t >> 3;
  const int gcol = (((t & 7) ^ (r0 & 7)) * 8);
  char* ldsbase  = (char*)&sm.stage[0][0];
  const int wofs = wv * 1024;

  const bf16_t* pA1 = A1 ? A1 : A2;
  const bf16_t* pA2 = A2 ? A2 : A1;
  const bf16_t* a1p0 = pA1 + (size_t)(m0 + r0) * sA1 + gcol;
  const bf16_t* a1p1 = pA1 + (size_t)(m0 + r0 + 32) * sA1 + gcol;
  const bf16_t* a2p0 = pA2 + (size_t)(m0 + r0) * sA2 + gcol;
  const bf16_t* a2p1 = pA2 + (size_t)(m0 + r0 + 32) * sA2 + gcol;
  const bf16_t* wp0  = W + (size_t)(n0 + r0) * sW + gcol;
  const bf16_t* wp1  = W + (size_t)(n0 + r0 + 32) * sW + gcol;
  const bf16_t* wp2  = W + (size_t)(n0 + r0 + 64) * sW + gcol;
  const bf16_t* wp3  = W + (size_t)(n0 + r0 + 96) * sW + gcol;

  const int nTot = n1 + n2;

  auto stage = [&](int j, int bf) {
    char* Ab = ldsbase + bf * BUFB + wofs;
    char* Bb = ldsbase + bf * BUFB + 8192 + wofs;
    const int k = j * BK;
    const bf16_t *a0, *a1;
    if (j < n1) { a0 = a1p0 + k; a1 = a1p1 + k; }
    else { const int k2 = k - n1 * BK; a0 = a2p0 + k2; a1 = a2p1 + k2; }
    gload16(a0, Ab);
    gload16(a1, Ab + 4096);
    gload16(wp0 + k, Bb);
    gload16(wp1 + k, Bb + 4096);
    gload16(wp2 + k, Bb + 8192);
    gload16(wp3 + k, Bb + 12288);
  };

  const int swz  = fr & 7;
  const int co0  = ((fq) ^ swz) * 16;
  const int co1  = ((4 + fq) ^ swz) * 16;
  const int arow0 = (wm * 32 + fr) * 128;
  const int arow1 = (wm * 32 + 16 + fr) * 128;
  const int brow  = (wn * 64 + fr) * 128;

  auto compute = [&](int bf) {
    const char* Ab = ldsbase + bf * BUFB;
    const char* Bb = Ab + 8192;
#pragma unroll
    for (int kk = 0; kk < 2; ++kk) {
      const int co = kk ? co1 : co0;
      bf16x8 av0 = *(const bf16x8*)(Ab + arow0 + co);
      bf16x8 av1 = *(const bf16x8*)(Ab + arow1 + co);
      bf16x8 bv[4];
#pragma unroll
      for (int j = 0; j < 4; ++j)
        bv[j] = *(const bf16x8*)(Bb + brow + j * 2048 + co);
#pragma unroll
      for (int j = 0; j < 4; ++j) {
        acc[0][j] = __builtin_amdgcn_mfma_f32_16x16x32_bf16(av0, bv[j], acc[0][j], 0, 0, 0);
        acc[1][j] = __builtin_amdgcn_mfma_f32_16x16x32_bf16(av1, bv[j], acc[1][j], 0, 0, 0);
      }
    }
  };

  stage(0, 0);
  if (nTot > 1) stage(1, 1);
  int cb = 0, sb = 2;
  for (int it = 0; it < nTot; ++it) {
    if (it == nTot - 1) {
      asm volatile("s_waitcnt vmcnt(0)" ::: "memory");
    } else {
      asm volatile("s_waitcnt vmcnt(6)" ::: "memory");
    }
    __builtin_amdgcn_s_barrier();
    if (it + 2 < nTot) stage(it + 2, sb);
    sb = (sb == 2) ? 0 : sb + 1;
    compute(cb);
    cb = (cb == 2) ? 0 : cb + 1;
  }
  __syncthreads();

  if (EPI == 1) {
#pragma unroll
    for (int i = 0; i < 2; ++i)
#pragma unroll
      for (int j = 0; j < 4; ++j)
#pragma unroll
        for (int v = 0; v < 4; ++v) {
          int row = wm * 32 + i * 16 + fq * 4 + v;
          int col = wn * 64 + j * 16 + fr;
          sm.gate[row * 129 + col] = acc[i][j][v] + bias4[j];
        }
    __syncthreads();
    const int u0 = n0 >> 2;
#pragma unroll
    for (int itc = 0; itc < 8; ++itc) {
      int ci = itc * 256 + t;
      int brw = ci >> 5;
      int ju  = ci & 31;
      const float* gp = &sm.gate[brw * 129 + ju * 4];
      float iv = fsigmoid(gp[0]);
      float fv = fsigmoid(gp[1]);
      float gv = ftanh(gp[2]);
      float ov = fsigmoid(gp[3]);
      size_t cix = (size_t)(m0 + brw) * H_SZ + (u0 + ju);
      float cn = fv * cbuf[cix] + iv * gv;
      cbuf[cix] = cn;
      hout[cix] = (bf16_t)(ov * ftanh(cn));
    }
  }

  if (EPI == 2) {
#pragma unroll
    for (int i = 0; i < 2; ++i)
#pragma unroll
      for (int j = 0; j < 4; ++j)
#pragma unroll
        for (int v = 0; v < 4; ++v) {
          int gr = m0 + wm * 32 + i * 16 + fq * 4 + v;
          int gc = n0 + wn * 64 + j * 16 + fr;
          int orig = (gr & 3) * H_SZ + (gr >> 2);
          float val = acc[i][j][v] + addm[(size_t)orig * H_SZ + gc];
          outb[(size_t)gr * H_SZ + gc] = (bf16_t)val;
        }
  }

  if (EPI == 3) {
#pragma unroll
    for (int i = 0; i < 2; ++i)
#pragma unroll
      for (int j = 0; j < 4; ++j)
#pragma unroll
        for (int v = 0; v < 4; ++v) {
          int m = m0 + wm * 32 + i * 16 + fq * 4 + v;
          int n = n0 + wn * 64 + j * 16 + fr;
          if (n < D_SZ) {
            int ts = m >> 9;
            int bb = m & 511;
            outf[((size_t)bb * TMAX + ts) * D_SZ + n] = acc[i][j][v] + bias4[j];
          }
        }
  }
}

// src (B,S,D) fp32 -> srcbf (S,B,DP) bf16, zero-padded d>=216
__global__ void k_convert_src(const float* __restrict__ src, bf16_t* __restrict__ dst) {
  int idx = blockIdx.x * 256 + threadIdx.x;
  int total = S_SZ * B_SZ * DP;
  if (idx >= total) return;
  int d = idx % DP;
  int r = idx / DP;
  int b = r % B_SZ;
  int tt = r / B_SZ;
  float v = (d < D_SZ) ? src[((size_t)b * S_SZ + tt) * D_SZ + d] : 0.f;
  dst[idx] = (bf16_t)v;
}

__global__ void k_build_wcat(const float* __restrict__ Wih, const float* __restrict__ Whh,
                             bf16_t* __restrict__ Wcat) {
  int idx = blockIdx.x * 256 + threadIdx.x;
  if (idx >= NG * KENC) return;
  int k = idx % KENC;
  int r = idx / KENC;
  int o = (r & 3) * H_SZ + (r >> 2);
  float v;
  if (k < D_SZ)      v = Wih[(size_t)o * D_SZ + k];
  else if (k < DP)   v = 0.f;
  else               v = Whh[(size_t)o * H_SZ + (k - DP)];
  Wcat[idx] = (bf16_t)v;
}

__global__ void k_build_wout(const float* __restrict__ Wout, bf16_t* __restrict__ WoutB,
                             bf16_t* __restrict__ WoutT) {
  int idx = blockIdx.x * 256 + threadIdx.x;
  if (idx < 256 * H_SZ) {
    int h = idx % H_SZ, d = idx / H_SZ;
    WoutB[idx] = (bf16_t)((d < D_SZ) ? Wout[(size_t)d * H_SZ + h] : 0.f);
  }
  if (idx < H_SZ * DP) {
    int d = idx % DP, h = idx / DP;
    WoutT[idx] = (bf16_t)((d < D_SZ) ? Wout[(size_t)d * H_SZ + h] : 0.f);
  }
}

__global__ void k_build_bias(const float* __restrict__ bih, const float* __restrict__ bhh,
                             const float* __restrict__ Wih, const float* __restrict__ bout,
                             float* __restrict__ biasE, float* __restrict__ biasD) {
  int r = blockIdx.x * 256 + threadIdx.x;
  if (r >= NG) return;
  int o = (r & 3) * H_SZ + (r >> 2);
  float be = bih[o] + bhh[o];
  biasE[r] = be;
  float s = 0.f;
  const float* wr = Wih + (size_t)o * D_SZ;
  for (int d = 0; d < D_SZ; ++d) s += wr[d] * bout[d];
  biasD[r] = be + s;
}

extern "C" void kernel_launch(void* const* d_in, const int* in_sizes, int n_in,
                              void* d_out, int out_size, void* d_ws, size_t ws_size,
                              hipStream_t stream) {
  const float* src  = (const float*)d_in[0];
  const float* Wih  = (const float*)d_in[1];
  const float* Whh  = (const float*)d_in[2];
  const float* bih  = (const float*)d_in[3];
  const float* bhh  = (const float*)d_in[4];
  const float* Wout = (const float*)d_in[5];
  const float* bout = (const float*)d_in[6];

  char* ws = (char*)d_ws;
  size_t off = 0;
  auto alloc = [&](size_t bytes) {
    void* p = ws + off;
    off = (off + bytes + 255) & ~(size_t)255;
    return p;
  };
  bf16_t* srcbf = (bf16_t*)alloc((size_t)S_SZ * B_SZ * DP * 2);
  bf16_t* Wcat  = (bf16_t*)alloc((size_t)NG * KENC * 2);
  bf16_t* Wdec  = (bf16_t*)alloc((size_t)NG * H_SZ * 2);
  bf16_t* WoutB = (bf16_t*)alloc((size_t)256 * H_SZ * 2);
  bf16_t* WoutT = (bf16_t*)alloc((size_t)H_SZ * DP * 2);
  float*  biasE = (float*)alloc((size_t)NG * 4);
  float*  biasD = (float*)alloc((size_t)NG * 4);
  float*  cbuf  = (float*)alloc((size_t)B_SZ * H_SZ * 4);
  bf16_t* hP0   = (bf16_t*)alloc((size_t)B_SZ * H_SZ * 2);
  bf16_t* hP1   = (bf16_t*)alloc((size_t)B_SZ * H_SZ * 2);
  bf16_t* Hs    = (bf16_t*)alloc((size_t)TMAX * B_SZ * H_SZ * 2);
  unsigned* flags = (unsigned*)alloc(1024);

  hipMemsetAsync(cbuf, 0, (size_t)B_SZ * H_SZ * 4, stream);
  hipMemsetAsync(hP0, 0, (size_t)B_SZ * H_SZ * 2, stream);
  hipMemsetAsync(flags, 0, 1024, stream);

  k_convert_src<<<(S_SZ * B_SZ * DP + 255) / 256, 256, 0, stream>>>(src, srcbf);
  k_build_wcat<<<(NG * KENC + 255) / 256, 256, 0, stream>>>(Wih, Whh, Wcat);
  k_build_wout<<<1024, 256, 0, stream>>>(Wout, WoutB, WoutT);
  k_build_bias<<<(NG + 255) / 256, 256, 0, stream>>>(bih, bhh, Wih, bout, biasE, biasD);

  // W_dec = W_hh(reordered) + W_ih(reordered) @ W_out   (M=4096, N=1024, K=256)
  gemm_step<2><<<dim3(H_SZ / BN, NG / BM), 256, 0, stream>>>(
      Wcat, KENC, DP / BK, nullptr, 0, 0, WoutT, DP,
      nullptr, nullptr, nullptr, Whh, Wdec, nullptr);

  // All 144 sequential steps: one persistent cooperative kernel, flag-synced.
  {
    const bf16_t* a_src = srcbf;
    const bf16_t* a_wc  = Wcat;
    const bf16_t* a_wd  = Wdec;
    const float*  a_bE  = biasE;
    const float*  a_bD  = biasD;
    float*        a_cb  = cbuf;
    bf16_t*       a_hA  = hP0;
    bf16_t*       a_hB  = hP1;
    bf16_t*       a_Hs  = Hs;
    unsigned*     a_fl  = flags;
    void* kargs[] = {&a_src, &a_wc, &a_wd, &a_bE, &a_bD,
                     &a_cb, &a_hA, &a_hB, &a_Hs, &a_fl};
    hipLaunchCooperativeKernel((void*)lstm_chain, dim3(256), dim3(256),
                               kargs, 0, stream);
  }

  // Final projection: Y(12288 x 216) = Hs(12288 x 1024) @ W_out^T + b_out
  gemm_step<3><<<dim3(2, (TMAX * B_SZ) / BM), 256, 0, stream>>>(
      nullptr, 0, 0, Hs, H_SZ, H_SZ / BK, WoutB, H_SZ,
      bout, nullptr, nullptr, nullptr, nullptr, (float*)d_out);
}

// Round 3
// 2269.019 us; speedup vs baseline: 1.1257x; 1.0708x over previous
//
#include <hip/hip_runtime.h>
#include <cstdint>
#include <cstddef>

// Problem constants
#define B_SZ 512
#define S_SZ 120
#define D_SZ 216
#define H_SZ 1024
#define NG   4096     // 4*H
#define DP   256      // D padded to multiple of BK
#define KENC 1280     // DP + H
#define TMAX 24

// GEMM tile config
#define BM 64
#define BN 128
#define BK 64

using bf16_t = __bf16;
using bf16x8 = __attribute__((ext_vector_type(8))) __bf16;
using f32x4  = __attribute__((ext_vector_type(4))) float;

__device__ __forceinline__ void gload16(const void* g, void* l) {
  __builtin_amdgcn_global_load_lds(
      (const __attribute__((address_space(1))) void*)g,
      (__attribute__((address_space(3))) void*)l, 16, 0, 0);
}
// Coherent variant for h (cross-XCD producer): sc0|sc1 bypasses potentially
// stale L1/L2 and reads from the device coherence point (MALL).
__device__ __forceinline__ void gload16c(const void* g, void* l) {
  __builtin_amdgcn_global_load_lds(
      (const __attribute__((address_space(1))) void*)g,
      (__attribute__((address_space(3))) void*)l, 16, 0, 0x11);
}

__device__ __forceinline__ float fsigmoid(float x) {
  x = fminf(fmaxf(x, -30.f), 30.f);
  return 1.f / (1.f + __expf(-x));
}
__device__ __forceinline__ float ftanh(float x) {
  x = fminf(fmaxf(x, -15.f), 15.f);
  float e = __expf(2.f * x);
  return (e - 1.f) / (e + 1.f);
}

// LDS: FOUR staging buffers (A 64x64 bf16 = 8KB + B 128x64 bf16 = 16KB each)
// for depth-3 prefetch, PLUS a separate gate region (disjoint, no union).
// Tiles stored [row][64] with XOR chunk swizzle applied on the GLOBAL fetch
// side: LDS slot (r, c) holds global 8-elem chunk c^(r&7).
#define BUFB 24576
struct __align__(16) Smem {
  bf16_t stage[4][(BM + BN) * BK];  // 98304 B
  float gate[BM * 129];             // 33024 B  (total 131328 B < 160 KiB)
};

// ---------------------------------------------------------------------------
// Persistent kernel: all 144 LSTM steps, ONE cooperative launch.
// Sync protocol (v3): per-WG monotone flags (value = completed steps), and
// the consumer waits ONCE PER STEP: a single vector load reads all 32 flags
// of its m-panel (lane i -> flag i), spin until __all(>= s). No per-iteration
// MALL polls; no atomic contention. In-loop waits are all counted vmcnt
// (waves 0/1: 8/4/0 ladder; waves 2/3: 16/8/0), issued by the OWNING wave
// BEFORE the shared barrier, so every wave's LDS data is complete when any
// wave computes on it. Depth-3 prefetch over 4 LDS buffers covers the ~900cy
// MALL latency of bypass h loads. h stores go sc0|sc1 straight to MALL; flag
// publish after per-wave store drain + barrier, so flag-visible => h-visible.
// Panels (m-rows) are fully independent pipelines: h[m-panel] is consumed
// only by the same panel's 32 blocks; no cross-panel sync at all.
// ---------------------------------------------------------------------------
__global__ __launch_bounds__(256, 1) void lstm_chain(
    const bf16_t* __restrict__ srcbf,
    const bf16_t* __restrict__ Wcat,
    const bf16_t* __restrict__ Wdec,
    const float* __restrict__ biasE,
    const float* __restrict__ biasD,
    float* __restrict__ cbuf,
    bf16_t* __restrict__ hA,
    bf16_t* __restrict__ hB,
    bf16_t* __restrict__ Hs,
    unsigned* __restrict__ flags)
{
  __shared__ Smem sm;
  const int t    = threadIdx.x;
  const int bid  = blockIdx.x;
  const int n0   = (bid & 31) * BN;   // x-fastest: W panels stay L2-resident
  const int m0   = (bid >> 5) * BM;
  const int lane = t & 63;
  const int wv   = t >> 6;
  const int wm   = wv >> 1, wn = wv & 1;
  const int fr   = lane & 15;
  const int fq   = lane >> 4;

  char* ldsbase = (char*)&sm.stage[0][0];

  // ---- staging geometry (wave-specialized) ----
  const int sw8   = (((lane & 7) ^ (lane >> 3)) & 7) * 8;  // swizzled col (elems)
  const int arow  = (wv & 1) * 32 + (lane >> 3);           // waves 0/1: A row
  const int wrow  = (wv & 1) * 64 + (lane >> 3);           // waves 2/3: W row
  const int aldso = (wv & 1) * 4096;
  const int wldso = 8192 + (wv & 1) * 8192;

  // ---- fragment read offsets (swizzle-aware, conflict-free) ----
  const int swz   = fr & 7;
  const int co0   = ((fq) ^ swz) * 16;
  const int co1   = ((4 + fq) ^ swz) * 16;
  const int arow0 = (wm * 32 + fr) * 128;
  const int arow1 = (wm * 32 + 16 + fr) * 128;
  const int brow  = (wn * 64 + fr) * 128;
  const int u0    = n0 >> 2;

  const int panel = m0 >> 6;
  unsigned* flg = flags + panel * 32;     // this panel's 32 producer flags
  unsigned* myf = flg + (n0 >> 7);        // our own flag (BN=128)
  const unsigned* myFlagAddr = flg + (lane & 31);

  auto stageA = [&](const bf16_t* base, int stride, int kelem, int buf, bool coh) {
    char* Ab = ldsbase + buf * BUFB + aldso;
    const bf16_t* p = base + (size_t)(m0 + arow) * stride + sw8 + kelem;
#pragma unroll
    for (int q = 0; q < 4; ++q) {
      if (coh) gload16c(p, Ab); else gload16(p, Ab);
      p += (size_t)8 * stride;
      Ab += 1024;
    }
  };
  auto stageW = [&](const bf16_t* Wb, int stride, int kelem, int buf) {
    char* Bb = ldsbase + buf * BUFB + wldso;
    const bf16_t* p = Wb + (size_t)(n0 + wrow) * stride + sw8 + kelem;
#pragma unroll
    for (int q = 0; q < 8; ++q) {
      gload16(p, Bb);
      p += (size_t)8 * stride;
      Bb += 1024;
    }
  };

  f32x4 acc[2][4];

  auto compute = [&](int bf) {
    const char* Ab = ldsbase + bf * BUFB;
    const char* Bb = Ab + 8192;
#pragma unroll
    for (int kk = 0; kk < 2; ++kk) {
      const int co = kk ? co1 : co0;
      bf16x8 av0 = *(const bf16x8*)(Ab + arow0 + co);
      bf16x8 av1 = *(const bf16x8*)(Ab + arow1 + co);
      bf16x8 bv[4];
#pragma unroll
      for (int j = 0; j < 4; ++j)
        bv[j] = *(const bf16x8*)(Bb + brow + j * 2048 + co);
#pragma unroll
      for (int j = 0; j < 4; ++j) {
        acc[0][j] = __builtin_amdgcn_mfma_f32_16x16x32_bf16(av0, bv[j], acc[0][j], 0, 0, 0);
        acc[1][j] = __builtin_amdgcn_mfma_f32_16x16x32_bf16(av1, bv[j], acc[1][j], 0, 0, 0);
      }
    }
  };

  // Once-per-step panel wait: one vector load covers all 32 panel flags.
  // Drains own vmcnt first (outstanding stages are L2-fast src/W loads).
  auto panelSpin = [&](unsigned need) {
    asm volatile("s_waitcnt vmcnt(0)" ::: "memory");
    for (;;) {
      unsigned v;
      asm volatile("global_load_dword %0, %1, off sc0 sc1\n\t"
                   "s_waitcnt vmcnt(0)"
                   : "=v"(v) : "v"(myFlagAddr) : "memory");
      if (__all((int)(v >= need))) break;
      __builtin_amdgcn_s_sleep(2);
    }
  };

  const bf16_t* hprev = hA;
  int cb = 0;

  // ---- prologue: stage step-0 slices 0,1,2 (src A + Wcat W), depth 3 ----
  if (wv < 2) {
    stageA(srcbf, DP, 0, 0, false);
    stageA(srcbf, DP, BK, 1, false);
    stageA(srcbf, DP, 2 * BK, 2, false);
  } else {
    stageW(Wcat, KENC, 0, 0);
    stageW(Wcat, KENC, BK, 1);
    stageW(Wcat, KENC, 2 * BK, 2);
  }

#pragma clang loop unroll(disable)
  for (int s = 0; s < 144; ++s) {
    const bool enc = (s <= 120);
    const int  xi  = (s < 120) ? s : 119;
    const bf16_t* Asrc = srcbf + (size_t)xi * B_SZ * DP;
    const int n1 = enc ? (DP / BK) : 0;
    const bf16_t* Wb  = enc ? Wcat : Wdec;
    const int     sWb = enc ? KENC : H_SZ;
    const float*  bias = enc ? biasE : biasD;
    bf16_t* hnext = (s < 120) ? ((s & 1) ? hA : hB)
                              : (Hs + (size_t)(s - 120) * B_SZ * H_SZ);
    const int nTot = n1 + H_SZ / BK;        // 20 enc-structured, 16 dec
    const bool nxtEnc = (s + 1 <= 120);
    const bool crossA = nxtEnc;             // waves 0/1 tail-stage next src
    const bool crossW = (s < 143);          // waves 2/3 always cross-stage
    const bf16_t* nxtW  = nxtEnc ? Wcat : Wdec;
    const int     nxtsW = nxtEnc ? KENC : H_SZ;
    const bf16_t* nxtA  = srcbf + (size_t)((s + 1 < 120) ? (s + 1) : 119) * B_SZ * DP;

    float bias4[4];
#pragma unroll
    for (int j = 0; j < 4; ++j) bias4[j] = bias[n0 + wn * 64 + j * 16 + fr];

#pragma unroll
    for (int i = 0; i < 2; ++i)
#pragma unroll
      for (int j = 0; j < 4; ++j) acc[i][j] = (f32x4){0.f, 0.f, 0.f, 0.f};

    for (int it = 0; it < nTot; ++it) {
      // Counted waits, issued by the OWNING wave BEFORE the barrier so all
      // waves may read the staged LDS after it. Tail ladder when no
      // cross-step staging keeps the "all but last-2-stages done" invariant.
      if (wv >= 2) {
        if (crossW || it < nTot - 2)
          asm volatile("s_waitcnt vmcnt(16)" ::: "memory");
        else if (it == nTot - 2)
          asm volatile("s_waitcnt vmcnt(8)" ::: "memory");
        else
          asm volatile("s_waitcnt vmcnt(0)" ::: "memory");
      } else {
        if (crossA || it < nTot - 2)
          asm volatile("s_waitcnt vmcnt(8)" ::: "memory");
        else if (it == nTot - 2)
          asm volatile("s_waitcnt vmcnt(4)" ::: "memory");
        else
          asm volatile("s_waitcnt vmcnt(0)" ::: "memory");
      }
      __builtin_amdgcn_s_barrier();

      const int j3 = it + 3;
      const int sbuf = (cb + 3) & 3;

      if (wv >= 2) {
        if (j3 < nTot)     stageW(Wb, sWb, j3 * BK, sbuf);
        else if (crossW)   stageW(nxtW, nxtsW, (j3 - nTot) * BK, sbuf);
      } else {
        // Once-per-step wait before the FIRST h slice (enc: j3=n1 at it==1).
        if (enc && it == 1 && s > 0) panelSpin((unsigned)s);
        if (j3 < nTot) {
          if (j3 < n1) stageA(Asrc, DP, j3 * BK, sbuf, false);
          else         stageA(hprev, H_SZ, (j3 - n1) * BK, sbuf, true);
        } else if (crossA) {
          stageA(nxtA, DP, (j3 - nTot) * BK, sbuf, false);
        }
      }

      compute(cb);
      cb = (cb + 1) & 3;
    }

    // ---- LSTM cell epilogue (gate region disjoint from staging buffers) ----
#pragma unroll
    for (int i = 0; i < 2; ++i)
#pragma unroll
      for (int j = 0; j < 4; ++j)
#pragma unroll
        for (int v = 0; v < 4; ++v) {
          int row = wm * 32 + i * 16 + fq * 4 + v;
          int col = wn * 64 + j * 16 + fr;
          sm.gate[row * 129 + col] = acc[i][j][v] + bias4[j];
        }
    __syncthreads();
#pragma unroll
    for (int itc = 0; itc < 8; ++itc) {
      int ci  = itc * 256 + t;
      int brw = ci >> 5;
      int ju  = ci & 31;
      const float* gp = &sm.gate[brw * 129 + ju * 4];
      float iv = fsigmoid(gp[0]);
      float fv = fsigmoid(gp[1]);
      float gv = ftanh(gp[2]);
      float ov = fsigmoid(gp[3]);
      size_t cix = (size_t)(m0 + brw) * H_SZ + (u0 + ju);
      float cn = fv * cbuf[cix] + iv * gv;   // cbuf is WG-private: plain path
      cbuf[cix] = cn;
      bf16_t hb = (bf16_t)(ov * ftanh(cn));
      uint32_t hv32 = (uint32_t)__builtin_bit_cast(uint16_t, hb);
      asm volatile("global_store_short %0, %1, off sc0 sc1"
                   :: "v"((uint16_t*)&hnext[cix]), "v"(hv32) : "memory");
    }
    // per-wave store drain, then barrier, then publish our flag:
    // flag visible at MALL => our h slice visible at MALL.
    asm volatile("s_waitcnt vmcnt(0)" ::: "memory");
    __syncthreads();
    if (t == 0) {
      unsigned fv2 = (unsigned)(s + 1);
      asm volatile("global_store_dword %0, %1, off sc0 sc1"
                   :: "v"(myf), "v"(fv2) : "memory");
    }

    // Deferred h pre-stage for decoder-structured next step (slices 0,1,2).
    // panelSpin establishes all producers done with step s; stage loads'
    // completion is guaranteed by next loop's pre-barrier vmcnt(8).
    if (s < 143 && !nxtEnc && wv < 2) {
      panelSpin((unsigned)(s + 1));
      stageA(hnext, H_SZ, 0, cb, true);
      stageA(hnext, H_SZ, BK, (cb + 1) & 3, true);
      stageA(hnext, H_SZ, 2 * BK, (cb + 2) & 3, true);
    }

    hprev = hnext;
  }
}

// ---------------------------------------------------------------------------
// Standalone GEMM (EPI=2 W_dec build, EPI=3 final projection)
// ---------------------------------------------------------------------------
template <int EPI>
__global__ __launch_bounds__(256, 1) void gemm_step(
    const bf16_t* __restrict__ A1, int sA1, int n1,
    const bf16_t* __restrict__ A2, int sA2, int n2,
    const bf16_t* __restrict__ W, int sW,
    const float* __restrict__ bias,
    float* __restrict__ cbuf, bf16_t* __restrict__ hout,
    const float* __restrict__ addm, bf16_t* __restrict__ outb,
    float* __restrict__ outf)
{
  __shared__ Smem sm;
  const int t    = threadIdx.x;
  const int m0   = blockIdx.y * BM;
  const int n0   = blockIdx.x * BN;
  const int lane = t & 63;
  const int wv   = t >> 6;
  const int wm   = wv >> 1, wn = wv & 1;
  const int fr   = lane & 15;
  const int fq   = lane >> 4;

  f32x4 acc[2][4] = {};

  float bias4[4];
  if (EPI == 1 || EPI == 3) {
#pragma unroll
    for (int j = 0; j < 4; ++j) {
      int col = n0 + wn * 64 + j * 16 + fr;
      bias4[j] = (EPI == 3 && col >= D_SZ) ? 0.f : bias[col];
    }
  }

  const int r0   = t >> 3;
  const int gcol = (((t & 7) ^ (r0 & 7)) * 8);
  char* ldsbase  = (char*)&sm.stage[0][0];
  const int wofs = wv * 1024;

  const bf16_t* pA1 = A1 ? A1 : A2;
  const bf16_t* pA2 = A2 ? A2 : A1;
  const bf16_t* a1p0 = pA1 + (size_t)(m0 + r0) * sA1 + gcol;
  const bf16_t* a1p1 = pA1 + (size_t)(m0 + r0 + 32) * sA1 + gcol;
  const bf16_t* a2p0 = pA2 + (size_t)(m0 + r0) * sA2 + gcol;
  const bf16_t* a2p1 = pA2 + (size_t)(m0 + r0 + 32) * sA2 + gcol;
  const bf16_t* wp0  = W + (size_t)(n0 + r0) * sW + gcol;
  const bf16_t* wp1  = W + (size_t)(n0 + r0 + 32) * sW + gcol;
  const bf16_t* wp2  = W + (size_t)(n0 + r0 + 64) * sW + gcol;
  const bf16_t* wp3  = W + (size_t)(n0 + r0 + 96) * sW + gcol;

  const int nTot = n1 + n2;

  auto stage = [&](int j, int bf) {
    char* Ab = ldsbase + bf * BUFB + wofs;
    char* Bb = ldsbase + bf * BUFB + 8192 + wofs;
    const int k = j * BK;
    const bf16_t *a0, *a1;
    if (j < n1) { a0 = a1p0 + k; a1 = a1p1 + k; }
    else { const int k2 = k - n1 * BK; a0 = a2p0 + k2; a1 = a2p1 + k2; }
    gload16(a0, Ab);
    gload16(a1, Ab + 4096);
    gload16(wp0 + k, Bb);
    gload16(wp1 + k, Bb + 4096);
    gload16(wp2 + k, Bb + 8192);
    gload16(wp3 + k, Bb + 12288);
  };

  const int swz  = fr & 7;
  const int co0  = ((fq) ^ swz) * 16;
  const int co1  = ((4 + fq) ^ swz) * 16;
  const int arow0 = (wm * 32 + fr) * 128;
  const int arow1 = (wm * 32 + 16 + fr) * 128;
  const int brow  = (wn * 64 + fr) * 128;

  auto compute = [&](int bf) {
    const char* Ab = ldsbase + bf * BUFB;
    const char* Bb = Ab + 8192;
#pragma unroll
    for (int kk = 0; kk < 2; ++kk) {
      const int co = kk ? co1 : co0;
      bf16x8 av0 = *(const bf16x8*)(Ab + arow0 + co);
      bf16x8 av1 = *(const bf16x8*)(Ab + arow1 + co);
      bf16x8 bv[4];
#pragma unroll
      for (int j = 0; j < 4; ++j)
        bv[j] = *(const bf16x8*)(Bb + brow + j * 2048 + co);
#pragma unroll
      for (int j = 0; j < 4; ++j) {
        acc[0][j] = __builtin_amdgcn_mfma_f32_16x16x32_bf16(av0, bv[j], acc[0][j], 0, 0, 0);
        acc[1][j] = __builtin_amdgcn_mfma_f32_16x16x32_bf16(av1, bv[j], acc[1][j], 0, 0, 0);
      }
    }
  };

  stage(0, 0);
  if (nTot > 1) stage(1, 1);
  int cb = 0, sb = 2;
  for (int it = 0; it < nTot; ++it) {
    if (it == nTot - 1) {
      asm volatile("s_waitcnt vmcnt(0)" ::: "memory");
    } else {
      asm volatile("s_waitcnt vmcnt(6)" ::: "memory");
    }
    __builtin_amdgcn_s_barrier();
    if (it + 2 < nTot) stage(it + 2, sb);
    sb = (sb == 2) ? 0 : sb + 1;
    compute(cb);
    cb = (cb == 2) ? 0 : cb + 1;
  }
  __syncthreads();

  if (EPI == 1) {
#pragma unroll
    for (int i = 0; i < 2; ++i)
#pragma unroll
      for (int j = 0; j < 4; ++j)
#pragma unroll
        for (int v = 0; v < 4; ++v) {
          int row = wm * 32 + i * 16 + fq * 4 + v;
          int col = wn * 64 + j * 16 + fr;
          sm.gate[row * 129 + col] = acc[i][j][v] + bias4[j];
        }
    __syncthreads();
    const int u0 = n0 >> 2;
#pragma unroll
    for (int itc = 0; itc < 8; ++itc) {
      int ci = itc * 256 + t;
      int brw = ci >> 5;
      int ju  = ci & 31;
      const float* gp = &sm.gate[brw * 129 + ju * 4];
      float iv = fsigmoid(gp[0]);
      float fv = fsigmoid(gp[1]);
      float gv = ftanh(gp[2]);
      float ov = fsigmoid(gp[3]);
      size_t cix = (size_t)(m0 + brw) * H_SZ + (u0 + ju);
      float cn = fv * cbuf[cix] + iv * gv;
      cbuf[cix] = cn;
      hout[cix] = (bf16_t)(ov * ftanh(cn));
    }
  }

  if (EPI == 2) {
#pragma unroll
    for (int i = 0; i < 2; ++i)
#pragma unroll
      for (int j = 0; j < 4; ++j)
#pragma unroll
        for (int v = 0; v < 4; ++v) {
          int gr = m0 + wm * 32 + i * 16 + fq * 4 + v;
          int gc = n0 + wn * 64 + j * 16 + fr;
          int orig = (gr & 3) * H_SZ + (gr >> 2);
          float val = acc[i][j][v] + addm[(size_t)orig * H_SZ + gc];
          outb[(size_t)gr * H_SZ + gc] = (bf16_t)val;
        }
  }

  if (EPI == 3) {
#pragma unroll
    for (int i = 0; i < 2; ++i)
#pragma unroll
      for (int j = 0; j < 4; ++j)
#pragma unroll
        for (int v = 0; v < 4; ++v) {
          int m = m0 + wm * 32 + i * 16 + fq * 4 + v;
          int n = n0 + wn * 64 + j * 16 + fr;
          if (n < D_SZ) {
            int ts = m >> 9;
            int bb = m & 511;
            outf[((size_t)bb * TMAX + ts) * D_SZ + n] = acc[i][j][v] + bias4[j];
          }
        }
  }
}

// src (B,S,D) fp32 -> srcbf (S,B,DP) bf16, zero-padded d>=216
__global__ void k_convert_src(const float* __restrict__ src, bf16_t* __restrict__ dst) {
  int idx = blockIdx.x * 256 + threadIdx.x;
  int total = S_SZ * B_SZ * DP;
  if (idx >= total) return;
  int d = idx % DP;
  int r = idx / DP;
  int b = r % B_SZ;
  int tt = r / B_SZ;
  float v = (d < D_SZ) ? src[((size_t)b * S_SZ + tt) * D_SZ + d] : 0.f;
  dst[idx] = (bf16_t)v;
}

__global__ void k_build_wcat(const float* __restrict__ Wih, const float* __restrict__ Whh,
                             bf16_t* __restrict__ Wcat) {
  int idx = blockIdx.x * 256 + threadIdx.x;
  if (idx >= NG * KENC) return;
  int k = idx % KENC;
  int r = idx / KENC;
  int o = (r & 3) * H_SZ + (r >> 2);
  float v;
  if (k < D_SZ)      v = Wih[(size_t)o * D_SZ + k];
  else if (k < DP)   v = 0.f;
  else               v = Whh[(size_t)o * H_SZ + (k - DP)];
  Wcat[idx] = (bf16_t)v;
}

__global__ void k_build_wout(const float* __restrict__ Wout, bf16_t* __restrict__ WoutB,
                             bf16_t* __restrict__ WoutT) {
  int idx = blockIdx.x * 256 + threadIdx.x;
  if (idx < 256 * H_SZ) {
    int h = idx % H_SZ, d = idx / H_SZ;
    WoutB[idx] = (bf16_t)((d < D_SZ) ? Wout[(size_t)d * H_SZ + h] : 0.f);
  }
  if (idx < H_SZ * DP) {
    int d = idx % DP, h = idx / DP;
    WoutT[idx] = (bf16_t)((d < D_SZ) ? Wout[(size_t)d * H_SZ + h] : 0.f);
  }
}

__global__ void k_build_bias(const float* __restrict__ bih, const float* __restrict__ bhh,
                             const float* __restrict__ Wih, const float* __restrict__ bout,
                             float* __restrict__ biasE, float* __restrict__ biasD) {
  int r = blockIdx.x * 256 + threadIdx.x;
  if (r >= NG) return;
  int o = (r & 3) * H_SZ + (r >> 2);
  float be = bih[o] + bhh[o];
  biasE[r] = be;
  float s = 0.f;
  const float* wr = Wih + (size_t)o * D_SZ;
  for (int d = 0; d < D_SZ; ++d) s += wr[d] * bout[d];
  biasD[r] = be + s;
}

extern "C" void kernel_launch(void* const* d_in, const int* in_sizes, int n_in,
                              void* d_out, int out_size, void* d_ws, size_t ws_size,
                              hipStream_t stream) {
  const float* src  = (const float*)d_in[0];
  const float* Wih  = (const float*)d_in[1];
  const float* Whh  = (const float*)d_in[2];
  const float* bih  = (const float*)d_in[3];
  const float* bhh  = (const float*)d_in[4];
  const float* Wout = (const float*)d_in[5];
  const float* bout = (const float*)d_in[6];

  char* ws = (char*)d_ws;
  size_t off = 0;
  auto alloc = [&](size_t bytes) {
    void* p = ws + off;
    off = (off + bytes + 255) & ~(size_t)255;
    return p;
  };
  bf16_t* srcbf = (bf16_t*)alloc((size_t)S_SZ * B_SZ * DP * 2);
  bf16_t* Wcat  = (bf16_t*)alloc((size_t)NG * KENC * 2);
  bf16_t* Wdec  = (bf16_t*)alloc((size_t)NG * H_SZ * 2);
  bf16_t* WoutB = (bf16_t*)alloc((size_t)256 * H_SZ * 2);
  bf16_t* WoutT = (bf16_t*)alloc((size_t)H_SZ * DP * 2);
  float*  biasE = (float*)alloc((size_t)NG * 4);
  float*  biasD = (float*)alloc((size_t)NG * 4);
  float*  cbuf  = (float*)alloc((size_t)B_SZ * H_SZ * 4);
  bf16_t* hP0   = (bf16_t*)alloc((size_t)B_SZ * H_SZ * 2);
  bf16_t* hP1   = (bf16_t*)alloc((size_t)B_SZ * H_SZ * 2);
  bf16_t* Hs    = (bf16_t*)alloc((size_t)TMAX * B_SZ * H_SZ * 2);
  unsigned* flags = (unsigned*)alloc(1024);

  hipMemsetAsync(cbuf, 0, (size_t)B_SZ * H_SZ * 4, stream);
  hipMemsetAsync(hP0, 0, (size_t)B_SZ * H_SZ * 2, stream);
  hipMemsetAsync(flags, 0, 1024, stream);

  k_convert_src<<<(S_SZ * B_SZ * DP + 255) / 256, 256, 0, stream>>>(src, srcbf);
  k_build_wcat<<<(NG * KENC + 255) / 256, 256, 0, stream>>>(Wih, Whh, Wcat);
  k_build_wout<<<1024, 256, 0, stream>>>(Wout, WoutB, WoutT);
  k_build_bias<<<(NG + 255) / 256, 256, 0, stream>>>(bih, bhh, Wih, bout, biasE, biasD);

  // W_dec = W_hh(reordered) + W_ih(reordered) @ W_out   (M=4096, N=1024, K=256)
  gemm_step<2><<<dim3(H_SZ / BN, NG / BM), 256, 0, stream>>>(
      Wcat, KENC, DP / BK, nullptr, 0, 0, WoutT, DP,
      nullptr, nullptr, nullptr, Whh, Wdec, nullptr);

  // All 144 sequential steps: one persistent cooperative kernel, flag-synced.
  {
    const bf16_t* a_src = srcbf;
    const bf16_t* a_wc  = Wcat;
    const bf16_t* a_wd  = Wdec;
    const float*  a_bE  = biasE;
    const float*  a_bD  = biasD;
    float*        a_cb  = cbuf;
    bf16_t*       a_hA  = hP0;
    bf16_t*       a_hB  = hP1;
    bf16_t*       a_Hs  = Hs;
    unsigned*     a_fl  = flags;
    void* kargs[] = {&a_src, &a_wc, &a_wd, &a_bE, &a_bD,
                     &a_cb, &a_hA, &a_hB, &a_Hs, &a_fl};
    hipLaunchCooperativeKernel((void*)lstm_chain, dim3(256), dim3(256),
                               kargs, 0, stream);
  }

  // Final projection: Y(12288 x 216) = Hs(12288 x 1024) @ W_out^T + b_out
  gemm_step<3><<<dim3(2, (TMAX * B_SZ) / BM), 256, 0, stream>>>(
      nullptr, 0, 0, Hs, H_SZ, H_SZ / BK, WoutB, H_SZ,
      bout, nullptr, nullptr, nullptr, nullptr, (float*)d_out);
}

// Round 4
// 1897.760 us; speedup vs baseline: 1.3460x; 1.1956x over previous
//
#include <hip/hip_runtime.h>
#include <cstdint>
#include <cstddef>

// Problem constants
#define B_SZ 512
#define S_SZ 120
#define D_SZ 216
#define H_SZ 1024
#define NG   4096     // 4*H
#define DP   256      // D padded to multiple of BK
#define KENC 1280     // DP + H
#define TMAX 24

// GEMM tile config
#define BM 64
#define BN 128
#define BK 64
#define NBUF 5        // lstm_chain staging buffers (depth-4 prefetch)

using bf16_t = __bf16;
using bf16x8 = __attribute__((ext_vector_type(8))) __bf16;
using f32x4  = __attribute__((ext_vector_type(4))) float;

__device__ __forceinline__ void gload16(const void* g, void* l) {
  __builtin_amdgcn_global_load_lds(
      (const __attribute__((address_space(1))) void*)g,
      (__attribute__((address_space(3))) void*)l, 16, 0, 0);
}
// Coherent variant for h (cross-XCD producer): sc0|sc1 bypasses potentially
// stale L1/L2 and reads from the device coherence point (MALL).
__device__ __forceinline__ void gload16c(const void* g, void* l) {
  __builtin_amdgcn_global_load_lds(
      (const __attribute__((address_space(1))) void*)g,
      (__attribute__((address_space(3))) void*)l, 16, 0, 0x11);
}

__device__ __forceinline__ float fsigmoid(float x) {
  x = fminf(fmaxf(x, -30.f), 30.f);
  return 1.f / (1.f + __expf(-x));
}
__device__ __forceinline__ float ftanh(float x) {
  x = fminf(fmaxf(x, -15.f), 15.f);
  float e = __expf(2.f * x);
  return (e - 1.f) / (e + 1.f);
}

// LDS: FIVE staging buffers (A 64x64 bf16 = 8KB + B 128x64 bf16 = 16KB each)
// for depth-4 prefetch, PLUS a disjoint gate region.
// Tiles stored [row][64] with XOR chunk swizzle applied on the GLOBAL fetch
// side: LDS slot (r, c) holds global 8-elem chunk c^(r&7).
#define BUFB 24576
struct __align__(16) Smem {
  bf16_t stage[NBUF][(BM + BN) * BK];  // 122880 B
  float gate[BM * 129];                // 33024 B  (total 155904 B < 160 KiB)
};

// ---------------------------------------------------------------------------
// Persistent kernel: all 144 LSTM steps, ONE cooperative launch, 256 WGs of
// 512 THREADS (8 waves = 2 waves/SIMD -> TLP hides LDS/MFMA/barrier latency;
// round-3's 4-wave/1-per-SIMD config was serial-latency-bound at 550cy/iter).
// Wave grid 2x4, wave-tile 32x32, acc 2x2. Staging is per-wave-uniform:
// every wave stages exactly 3 loads per k-slice (1 A-chunk rows 8w..8w+7 +
// 2 W-chunks rows 16w..16w+15), so counted vmcnt is exact per wave:
// steady-state vmcnt(9) (= 3 newer slices in flight), tail 9/6/3/0.
// Depth-4 prefetch over 5 buffers covers the ~900cy MALL latency of bypass
// h loads. Sync: per-WG monotone flags (value = steps completed); consumer
// spins ONCE PER STEP on a 32-flag vector read (lane i -> panel flag i).
// h stores go sc0|sc1 straight to MALL; flag publish after per-wave store
// drain + barrier, so flag-visible => h-visible. Panels are independent.
// ---------------------------------------------------------------------------
__global__ __launch_bounds__(512, 1) void lstm_chain(
    const bf16_t* __restrict__ srcbf,
    const bf16_t* __restrict__ Wcat,
    const bf16_t* __restrict__ Wdec,
    const float* __restrict__ biasE,
    const float* __restrict__ biasD,
    float* __restrict__ cbuf,
    bf16_t* __restrict__ hA,
    bf16_t* __restrict__ hB,
    bf16_t* __restrict__ Hs,
    unsigned* __restrict__ flags)
{
  __shared__ Smem sm;
  const int t    = threadIdx.x;
  const int bid  = blockIdx.x;
  const int n0   = (bid & 31) * BN;   // x-fastest: W panels stay L2-resident
  const int m0   = (bid >> 5) * BM;
  const int lane = t & 63;
  const int wv   = t >> 6;            // 0..7
  const int wm   = wv >> 2;           // 0..1 (row block)
  const int wn   = wv & 3;            // 0..3 (col block)
  const int fr   = lane & 15;
  const int fq   = lane >> 4;

  char* ldsbase = (char*)&sm.stage[0][0];

  // ---- staging geometry (uniform: each wave = 1 A-chunk + 2 W-chunks) ----
  const int sgrp = lane >> 3;                        // 0..7 row in group
  const int sw8  = (((lane & 7) ^ sgrp) & 7) * 8;    // swizzled col (elems)
  const int aRowOff = 8 * wv + sgrp;                 // A rows 8w..8w+7
  const int wRowOff = 16 * wv + sgrp;                // W rows 16w..16w+15

  // ---- fragment read offsets (swizzle-aware) ----
  const int swz   = fr & 7;
  const int co0   = ((fq) ^ swz) * 16;
  const int co1   = ((4 + fq) ^ swz) * 16;
  const int arow0 = (wm * 32 + fr) * 128;
  const int arow1 = (wm * 32 + 16 + fr) * 128;
  const int brow  = 8192 + (wn * 32 + fr) * 128;
  const int u0    = n0 >> 2;

  const int panel = m0 >> 6;
  unsigned* flg = flags + panel * 32;     // this panel's 32 producer flags
  unsigned* myf = flg + (n0 >> 7);        // our own flag (BN=128)
  const unsigned* myFlagAddr = flg + (lane & 31);

  // stage one k-slice: 1 A gload + 2 W gloads per wave (3 vmcnt events)
  auto stageSlice = [&](const bf16_t* Ab, int sA, int ka, bool coh,
                        const bf16_t* Wb, int sW2, int kw, int buf) {
    char* lb = ldsbase + buf * BUFB;
    const bf16_t* ap = Ab + (size_t)(m0 + aRowOff) * sA + sw8 + ka;
    if (coh) gload16c(ap, lb + wv * 1024);
    else     gload16 (ap, lb + wv * 1024);
    const bf16_t* wp = Wb + (size_t)(n0 + wRowOff) * sW2 + sw8 + kw;
    gload16(wp, lb + 8192 + wv * 2048);
    gload16(wp + (size_t)8 * sW2, lb + 8192 + wv * 2048 + 1024);
  };

  f32x4 acc[2][2];

  auto compute = [&](int bf) {
    const char* Lb = ldsbase + bf * BUFB;
#pragma unroll
    for (int kk = 0; kk < 2; ++kk) {
      const int co = kk ? co1 : co0;
      bf16x8 av0 = *(const bf16x8*)(Lb + arow0 + co);
      bf16x8 av1 = *(const bf16x8*)(Lb + arow1 + co);
      bf16x8 bv0 = *(const bf16x8*)(Lb + brow + co);
      bf16x8 bv1 = *(const bf16x8*)(Lb + brow + 2048 + co);
      acc[0][0] = __builtin_amdgcn_mfma_f32_16x16x32_bf16(av0, bv0, acc[0][0], 0, 0, 0);
      acc[0][1] = __builtin_amdgcn_mfma_f32_16x16x32_bf16(av0, bv1, acc[0][1], 0, 0, 0);
      acc[1][0] = __builtin_amdgcn_mfma_f32_16x16x32_bf16(av1, bv0, acc[1][0], 0, 0, 0);
      acc[1][1] = __builtin_amdgcn_mfma_f32_16x16x32_bf16(av1, bv1, acc[1][1], 0, 0, 0);
    }
  };

  // Once-per-step panel wait: one vector load covers all 32 panel flags.
  auto panelSpin = [&](unsigned need) {
    asm volatile("s_waitcnt vmcnt(0)" ::: "memory");
    for (;;) {
      unsigned v;
      asm volatile("global_load_dword %0, %1, off sc0 sc1\n\t"
                   "s_waitcnt vmcnt(0)"
                   : "=v"(v) : "v"(myFlagAddr) : "memory");
      if (__all((int)(v >= need))) break;
      __builtin_amdgcn_s_sleep(2);
    }
  };

  const bf16_t* hprev = hA;
  int cb = 0;

  // ---- prologue: stage step-0 slices 0..3 (all src/Wcat), depth 4 ----
  stageSlice(srcbf, DP, 0,      false, Wcat, KENC, 0,      0);
  stageSlice(srcbf, DP, BK,     false, Wcat, KENC, BK,     1);
  stageSlice(srcbf, DP, 2 * BK, false, Wcat, KENC, 2 * BK, 2);
  stageSlice(srcbf, DP, 3 * BK, false, Wcat, KENC, 3 * BK, 3);

#pragma clang loop unroll(disable)
  for (int s = 0; s < 144; ++s) {
    const bool enc = (s <= 120);
    const int  xi  = (s < 120) ? s : 119;
    const bf16_t* Asrc = srcbf + (size_t)xi * B_SZ * DP;
    const int n1 = enc ? (DP / BK) : 0;
    const bf16_t* Wb  = enc ? Wcat : Wdec;
    const int     sWb = enc ? KENC : H_SZ;
    const float*  bias = enc ? biasE : biasD;
    bf16_t* hnext = (s < 120) ? ((s & 1) ? hA : hB)
                              : (Hs + (size_t)(s - 120) * B_SZ * H_SZ);
    const int nTot = n1 + H_SZ / BK;        // 20 enc-structured, 16 dec
    const bool nxtEnc = (s + 1 <= 120);
    const bool crossA = (s < 143) && nxtEnc;  // in-loop cross-stage (src-next)
    const bf16_t* nxtW  = nxtEnc ? Wcat : Wdec;
    const int     nxtsW = nxtEnc ? KENC : H_SZ;
    const bf16_t* nxtA  = srcbf + (size_t)((s + 1 < 120) ? (s + 1) : 119) * B_SZ * DP;

    float bias2[2];
#pragma unroll
    for (int j = 0; j < 2; ++j) bias2[j] = bias[n0 + wn * 32 + j * 16 + fr];

#pragma unroll
    for (int i = 0; i < 2; ++i)
#pragma unroll
      for (int j = 0; j < 2; ++j) acc[i][j] = (f32x4){0.f, 0.f, 0.f, 0.f};

    for (int it = 0; it < nTot; ++it) {
      // Per-wave counted wait: slice `it` (3 loads) done when <= 3*(slices
      // still newer) remain. Steady state 9; tail ladder 9/6/3/0.
      const int rem = nTot - it;
      if (crossA || rem >= 4)
        asm volatile("s_waitcnt vmcnt(9)" ::: "memory");
      else if (rem == 3)
        asm volatile("s_waitcnt vmcnt(6)" ::: "memory");
      else if (rem == 2)
        asm volatile("s_waitcnt vmcnt(3)" ::: "memory");
      else
        asm volatile("s_waitcnt vmcnt(0)" ::: "memory");
      __builtin_amdgcn_s_barrier();

      const int j4 = it + 4;
      const int sbuf = (cb + 4 >= NBUF) ? cb - 1 : cb + 4;

      if (j4 < nTot) {
        if (j4 < n1) {
          stageSlice(Asrc, DP, j4 * BK, false, Wb, sWb, j4 * BK, sbuf);
        } else {
          // first h slice of an encoder step: once-per-step panel wait
          if (enc && j4 == n1 && s > 0) panelSpin((unsigned)s);
          stageSlice(hprev, H_SZ, (j4 - n1) * BK, true, Wb, sWb, j4 * BK, sbuf);
        }
      } else if (crossA) {
        const int q = j4 - nTot;   // 0..3: next encoder step's src slices
        stageSlice(nxtA, DP, q * BK, false, nxtW, nxtsW, q * BK, sbuf);
      }

      compute(cb);
      cb = (cb == NBUF - 1) ? 0 : cb + 1;
    }

    // ---- LSTM cell epilogue (gate region disjoint from staging buffers) ----
#pragma unroll
    for (int i = 0; i < 2; ++i)
#pragma unroll
      for (int j = 0; j < 2; ++j)
#pragma unroll
        for (int v = 0; v < 4; ++v) {
          int row = wm * 32 + i * 16 + fq * 4 + v;
          int col = wn * 32 + j * 16 + fr;
          sm.gate[row * 129 + col] = acc[i][j][v] + bias2[j];
        }
    __syncthreads();
#pragma unroll
    for (int itc = 0; itc < 4; ++itc) {
      int ci  = itc * 512 + t;
      int brw = ci >> 5;   // 0..63 local batch row
      int ju  = ci & 31;   // 0..31 local unit
      const float* gp = &sm.gate[brw * 129 + ju * 4];
      float iv = fsigmoid(gp[0]);
      float fv = fsigmoid(gp[1]);
      float gv = ftanh(gp[2]);
      float ov = fsigmoid(gp[3]);
      size_t cix = (size_t)(m0 + brw) * H_SZ + (u0 + ju);
      float cn = fv * cbuf[cix] + iv * gv;   // cbuf is WG-private: plain path
      cbuf[cix] = cn;
      bf16_t hb = (bf16_t)(ov * ftanh(cn));
      uint32_t hv32 = (uint32_t)__builtin_bit_cast(uint16_t, hb);
      asm volatile("global_store_short %0, %1, off sc0 sc1"
                   :: "v"((uint16_t*)&hnext[cix]), "v"(hv32) : "memory");
    }
    // per-wave store drain, then barrier, then publish our flag:
    // flag visible at MALL => our h slice visible at MALL.
    asm volatile("s_waitcnt vmcnt(0)" ::: "memory");
    __syncthreads();
    if (t == 0) {
      unsigned fv2 = (unsigned)(s + 1);
      asm volatile("global_store_dword %0, %1, off sc0 sc1"
                   :: "v"(myf), "v"(fv2) : "memory");
    }

    // Deferred staging for decoder-structured next step (slices 0..3 = h).
    // panelSpin establishes all producers done with step s; completion of
    // these loads is covered by next step's it=0 vmcnt(9).
    if (s < 143 && !nxtEnc) {
      panelSpin((unsigned)(s + 1));
      int b = cb;
#pragma unroll
      for (int q = 0; q < 4; ++q) {
        stageSlice(hnext, H_SZ, q * BK, true, Wdec, H_SZ, q * BK, b);
        b = (b == NBUF - 1) ? 0 : b + 1;
      }
    }

    hprev = hnext;
  }
}

// ---------------------------------------------------------------------------
// Standalone GEMM (EPI=2 W_dec build, EPI=3 final projection) — unchanged.
// ---------------------------------------------------------------------------
template <int EPI>
__global__ __launch_bounds__(256, 1) void gemm_step(
    const bf16_t* __restrict__ A1, int sA1, int n1,
    const bf16_t* __restrict__ A2, int sA2, int n2,
    const bf16_t* __restrict__ W, int sW,
    const float* __restrict__ bias,
    float* __restrict__ cbuf, bf16_t* __restrict__ hout,
    const float* __restrict__ addm, bf16_t* __restrict__ outb,
    float* __restrict__ outf)
{
  __shared__ Smem sm;
  const int t    = threadIdx.x;
  const int m0   = blockIdx.y * BM;
  const int n0   = blockIdx.x * BN;
  const int lane = t & 63;
  const int wv   = t >> 6;
  const int wm   = wv >> 1, wn = wv & 1;
  const int fr   = lane & 15;
  const int fq   = lane >> 4;

  f32x4 acc[2][4] = {};

  float bias4[4];
  if (EPI == 1 || EPI == 3) {
#pragma unroll
    for (int j = 0; j < 4; ++j) {
      int col = n0 + wn * 64 + j * 16 + fr;
      bias4[j] = (EPI == 3 && col >= D_SZ) ? 0.f : bias[col];
    }
  }

  const int r0   = t >> 3;
  const int gcol = (((t & 7) ^ (r0 & 7)) * 8);
  char* ldsbase  = (char*)&sm.stage[0][0];
  const int wofs = wv * 1024;

  const bf16_t* pA1 = A1 ? A1 : A2;
  const bf16_t* pA2 = A2 ? A2 : A1;
  const bf16_t* a1p0 = pA1 + (size_t)(m0 + r0) * sA1 + gcol;
  const bf16_t* a1p1 = pA1 + (size_t)(m0 + r0 + 32) * sA1 + gcol;
  const bf16_t* a2p0 = pA2 + (size_t)(m0 + r0) * sA2 + gcol;
  const bf16_t* a2p1 = pA2 + (size_t)(m0 + r0 + 32) * sA2 + gcol;
  const bf16_t* wp0  = W + (size_t)(n0 + r0) * sW + gcol;
  const bf16_t* wp1  = W + (size_t)(n0 + r0 + 32) * sW + gcol;
  const bf16_t* wp2  = W + (size_t)(n0 + r0 + 64) * sW + gcol;
  const bf16_t* wp3  = W + (size_t)(n0 + r0 + 96) * sW + gcol;

  const int nTot = n1 + n2;

  auto stage = [&](int j, int bf) {
    char* Ab = ldsbase + bf * BUFB + wofs;
    char* Bb = ldsbase + bf * BUFB + 8192 + wofs;
    const int k = j * BK;
    const bf16_t *a0, *a1;
    if (j < n1) { a0 = a1p0 + k; a1 = a1p1 + k; }
    else { const int k2 = k - n1 * BK; a0 = a2p0 + k2; a1 = a2p1 + k2; }
    gload16(a0, Ab);
    gload16(a1, Ab + 4096);
    gload16(wp0 + k, Bb);
    gload16(wp1 + k, Bb + 4096);
    gload16(wp2 + k, Bb + 8192);
    gload16(wp3 + k, Bb + 12288);
  };

  const int swz  = fr & 7;
  const int co0  = ((fq) ^ swz) * 16;
  const int co1  = ((4 + fq) ^ swz) * 16;
  const int arow0 = (wm * 32 + fr) * 128;
  const int arow1 = (wm * 32 + 16 + fr) * 128;
  const int brow  = (wn * 64 + fr) * 128;

  auto compute = [&](int bf) {
    const char* Ab = ldsbase + bf * BUFB;
    const char* Bb = Ab + 8192;
#pragma unroll
    for (int kk = 0; kk < 2; ++kk) {
      const int co = kk ? co1 : co0;
      bf16x8 av0 = *(const bf16x8*)(Ab + arow0 + co);
      bf16x8 av1 = *(const bf16x8*)(Ab + arow1 + co);
      bf16x8 bv[4];
#pragma unroll
      for (int j = 0; j < 4; ++j)
        bv[j] = *(const bf16x8*)(Bb + brow + j * 2048 + co);
#pragma unroll
      for (int j = 0; j < 4; ++j) {
        acc[0][j] = __builtin_amdgcn_mfma_f32_16x16x32_bf16(av0, bv[j], acc[0][j], 0, 0, 0);
        acc[1][j] = __builtin_amdgcn_mfma_f32_16x16x32_bf16(av1, bv[j], acc[1][j], 0, 0, 0);
      }
    }
  };

  stage(0, 0);
  if (nTot > 1) stage(1, 1);
  int cb = 0, sb = 2;
  for (int it = 0; it < nTot; ++it) {
    if (it == nTot - 1) {
      asm volatile("s_waitcnt vmcnt(0)" ::: "memory");
    } else {
      asm volatile("s_waitcnt vmcnt(6)" ::: "memory");
    }
    __builtin_amdgcn_s_barrier();
    if (it + 2 < nTot) stage(it + 2, sb);
    sb = (sb == 2) ? 0 : sb + 1;
    compute(cb);
    cb = (cb == 2) ? 0 : cb + 1;
  }
  __syncthreads();

  if (EPI == 1) {
#pragma unroll
    for (int i = 0; i < 2; ++i)
#pragma unroll
      for (int j = 0; j < 4; ++j)
#pragma unroll
        for (int v = 0; v < 4; ++v) {
          int row = wm * 32 + i * 16 + fq * 4 + v;
          int col = wn * 64 + j * 16 + fr;
          sm.gate[row * 129 + col] = acc[i][j][v] + bias4[j];
        }
    __syncthreads();
    const int u0 = n0 >> 2;
#pragma unroll
    for (int itc = 0; itc < 8; ++itc) {
      int ci = itc * 256 + t;
      int brw = ci >> 5;
      int ju  = ci & 31;
      const float* gp = &sm.gate[brw * 129 + ju * 4];
      float iv = fsigmoid(gp[0]);
      float fv = fsigmoid(gp[1]);
      float gv = ftanh(gp[2]);
      float ov = fsigmoid(gp[3]);
      size_t cix = (size_t)(m0 + brw) * H_SZ + (u0 + ju);
      float cn = fv * cbuf[cix] + iv * gv;
      cbuf[cix] = cn;
      hout[cix] = (bf16_t)(ov * ftanh(cn));
    }
  }

  if (EPI == 2) {
#pragma unroll
    for (int i = 0; i < 2; ++i)
#pragma unroll
      for (int j = 0; j < 4; ++j)
#pragma unroll
        for (int v = 0; v < 4; ++v) {
          int gr = m0 + wm * 32 + i * 16 + fq * 4 + v;
          int gc = n0 + wn * 64 + j * 16 + fr;
          int orig = (gr & 3) * H_SZ + (gr >> 2);
          float val = acc[i][j][v] + addm[(size_t)orig * H_SZ + gc];
          outb[(size_t)gr * H_SZ + gc] = (bf16_t)val;
        }
  }

  if (EPI == 3) {
#pragma unroll
    for (int i = 0; i < 2; ++i)
#pragma unroll
      for (int j = 0; j < 4; ++j)
#pragma unroll
        for (int v = 0; v < 4; ++v) {
          int m = m0 + wm * 32 + i * 16 + fq * 4 + v;
          int n = n0 + wn * 64 + j * 16 + fr;
          if (n < D_SZ) {
            int ts = m >> 9;
            int bb = m & 511;
            outf[((size_t)bb * TMAX + ts) * D_SZ + n] = acc[i][j][v] + bias4[j];
          }
        }
  }
}

// src (B,S,D) fp32 -> srcbf (S,B,DP) bf16, zero-padded d>=216
__global__ void k_convert_src(const float* __restrict__ src, bf16_t* __restrict__ dst) {
  int idx = blockIdx.x * 256 + threadIdx.x;
  int total = S_SZ * B_SZ * DP;
  if (idx >= total) return;
  int d = idx % DP;
  int r = idx / DP;
  int b = r % B_SZ;
  int tt = r / B_SZ;
  float v = (d < D_SZ) ? src[((size_t)b * S_SZ + tt) * D_SZ + d] : 0.f;
  dst[idx] = (bf16_t)v;
}

__global__ void k_build_wcat(const float* __restrict__ Wih, const float* __restrict__ Whh,
                             bf16_t* __restrict__ Wcat) {
  int idx = blockIdx.x * 256 + threadIdx.x;
  if (idx >= NG * KENC) return;
  int k = idx % KENC;
  int r = idx / KENC;
  int o = (r & 3) * H_SZ + (r >> 2);
  float v;
  if (k < D_SZ)      v = Wih[(size_t)o * D_SZ + k];
  else if (k < DP)   v = 0.f;
  else               v = Whh[(size_t)o * H_SZ + (k - DP)];
  Wcat[idx] = (bf16_t)v;
}

__global__ void k_build_wout(const float* __restrict__ Wout, bf16_t* __restrict__ WoutB,
                             bf16_t* __restrict__ WoutT) {
  int idx = blockIdx.x * 256 + threadIdx.x;
  if (idx < 256 * H_SZ) {
    int h = idx % H_SZ, d = idx / H_SZ;
    WoutB[idx] = (bf16_t)((d < D_SZ) ? Wout[(size_t)d * H_SZ + h] : 0.f);
  }
  if (idx < H_SZ * DP) {
    int d = idx % DP, h = idx / DP;
    WoutT[idx] = (bf16_t)((d < D_SZ) ? Wout[(size_t)d * H_SZ + h] : 0.f);
  }
}

__global__ void k_build_bias(const float* __restrict__ bih, const float* __restrict__ bhh,
                             const float* __restrict__ Wih, const float* __restrict__ bout,
                             float* __restrict__ biasE, float* __restrict__ biasD) {
  int r = blockIdx.x * 256 + threadIdx.x;
  if (r >= NG) return;
  int o = (r & 3) * H_SZ + (r >> 2);
  float be = bih[o] + bhh[o];
  biasE[r] = be;
  float s = 0.f;
  const float* wr = Wih + (size_t)o * D_SZ;
  for (int d = 0; d < D_SZ; ++d) s += wr[d] * bout[d];
  biasD[r] = be + s;
}

extern "C" void kernel_launch(void* const* d_in, const int* in_sizes, int n_in,
                              void* d_out, int out_size, void* d_ws, size_t ws_size,
                              hipStream_t stream) {
  const float* src  = (const float*)d_in[0];
  const float* Wih  = (const float*)d_in[1];
  const float* Whh  = (const float*)d_in[2];
  const float* bih  = (const float*)d_in[3];
  const float* bhh  = (const float*)d_in[4];
  const float* Wout = (const float*)d_in[5];
  const float* bout = (const float*)d_in[6];

  char* ws = (char*)d_ws;
  size_t off = 0;
  auto alloc = [&](size_t bytes) {
    void* p = ws + off;
    off = (off + bytes + 255) & ~(size_t)255;
    return p;
  };
  bf16_t* srcbf = (bf16_t*)alloc((size_t)S_SZ * B_SZ * DP * 2);
  bf16_t* Wcat  = (bf16_t*)alloc((size_t)NG * KENC * 2);
  bf16_t* Wdec  = (bf16_t*)alloc((size_t)NG * H_SZ * 2);
  bf16_t* WoutB = (bf16_t*)alloc((size_t)256 * H_SZ * 2);
  bf16_t* WoutT = (bf16_t*)alloc((size_t)H_SZ * DP * 2);
  float*  biasE = (float*)alloc((size_t)NG * 4);
  float*  biasD = (float*)alloc((size_t)NG * 4);
  float*  cbuf  = (float*)alloc((size_t)B_SZ * H_SZ * 4);
  bf16_t* hP0   = (bf16_t*)alloc((size_t)B_SZ * H_SZ * 2);
  bf16_t* hP1   = (bf16_t*)alloc((size_t)B_SZ * H_SZ * 2);
  bf16_t* Hs    = (bf16_t*)alloc((size_t)TMAX * B_SZ * H_SZ * 2);
  unsigned* flags = (unsigned*)alloc(1024);

  hipMemsetAsync(cbuf, 0, (size_t)B_SZ * H_SZ * 4, stream);
  hipMemsetAsync(hP0, 0, (size_t)B_SZ * H_SZ * 2, stream);
  hipMemsetAsync(flags, 0, 1024, stream);

  k_convert_src<<<(S_SZ * B_SZ * DP + 255) / 256, 256, 0, stream>>>(src, srcbf);
  k_build_wcat<<<(NG * KENC + 255) / 256, 256, 0, stream>>>(Wih, Whh, Wcat);
  k_build_wout<<<1024, 256, 0, stream>>>(Wout, WoutB, WoutT);
  k_build_bias<<<(NG + 255) / 256, 256, 0, stream>>>(bih, bhh, Wih, bout, biasE, biasD);

  // W_dec = W_hh(reordered) + W_ih(reordered) @ W_out   (M=4096, N=1024, K=256)
  gemm_step<2><<<dim3(H_SZ / BN, NG / BM), 256, 0, stream>>>(
      Wcat, KENC, DP / BK, nullptr, 0, 0, WoutT, DP,
      nullptr, nullptr, nullptr, Whh, Wdec, nullptr);

  // All 144 sequential steps: one persistent cooperative kernel, 512 threads.
  {
    const bf16_t* a_src = srcbf;
    const bf16_t* a_wc  = Wcat;
    const bf16_t* a_wd  = Wdec;
    const float*  a_bE  = biasE;
    const float*  a_bD  = biasD;
    float*        a_cb  = cbuf;
    bf16_t*       a_hA  = hP0;
    bf16_t*       a_hB  = hP1;
    bf16_t*       a_Hs  = Hs;
    unsigned*     a_fl  = flags;
    void* kargs[] = {&a_src, &a_wc, &a_wd, &a_bE, &a_bD,
                     &a_cb, &a_hA, &a_hB, &a_Hs, &a_fl};
    hipLaunchCooperativeKernel((void*)lstm_chain, dim3(256), dim3(512),
                               kargs, 0, stream);
  }

  // Final projection: Y(12288 x 216) = Hs(12288 x 1024) @ W_out^T + b_out
  gemm_step<3><<<dim3(2, (TMAX * B_SZ) / BM), 256, 0, stream>>>(
      nullptr, 0, 0, Hs, H_SZ, H_SZ / BK, WoutB, H_SZ,
      bout, nullptr, nullptr, nullptr, nullptr, (float*)d_out);
}

// Round 5
// 1731.100 us; speedup vs baseline: 1.4755x; 1.0963x over previous
//
#include <hip/hip_runtime.h>
#include <cstdint>
#include <cstddef>

// Problem constants
#define B_SZ 512
#define S_SZ 120
#define D_SZ 216
#define H_SZ 1024
#define NG   4096     // 4*H
#define DP   256      // D padded to multiple of BK
#define KENC 1280     // DP + H
#define TMAX 24

// GEMM tile config
#define BM 64
#define BN 128
#define BK 64
#define NBUF 5        // lstm_chain staging buffers (depth-4 prefetch)

using bf16_t = __bf16;
using bf16x8 = __attribute__((ext_vector_type(8))) __bf16;
using f32x4  = __attribute__((ext_vector_type(4))) float;

__device__ __forceinline__ void gload16(const void* g, void* l) {
  __builtin_amdgcn_global_load_lds(
      (const __attribute__((address_space(1))) void*)g,
      (__attribute__((address_space(3))) void*)l, 16, 0, 0);
}
// Coherent variant for h (cross-XCD producer): sc0|sc1 bypasses potentially
// stale L1/L2 and reads from the device coherence point (MALL).
__device__ __forceinline__ void gload16c(const void* g, void* l) {
  __builtin_amdgcn_global_load_lds(
      (const __attribute__((address_space(1))) void*)g,
      (__attribute__((address_space(3))) void*)l, 16, 0, 0x11);
}

__device__ __forceinline__ float fsigmoid(float x) {
  x = fminf(fmaxf(x, -30.f), 30.f);
  return 1.f / (1.f + __expf(-x));
}
__device__ __forceinline__ float ftanh(float x) {
  x = fminf(fmaxf(x, -15.f), 15.f);
  float e = __expf(2.f * x);
  return (e - 1.f) / (e + 1.f);
}

#define BUFB 24576

// lstm_chain LDS: FIVE staging buffers (A 64x64 bf16 = 8KB + B 128x64 bf16 =
// 16KB each) for depth-4 prefetch, PLUS a disjoint gate region with stride
// 132 floats (132 = 4 mod 32 -> conflict-free f32x4 reads, 2-way-free writes;
// 16B-aligned rows since 132*4 = 528 = 33*16).
struct __align__(16) SmemChain {
  bf16_t stage[NBUF][(BM + BN) * BK];  // 122880 B
  float gate[BM * 132];                // 33792 B  (total 156672 B < 160 KiB)
};

// gemm_step LDS (original baseline layout, union: 73728 B)
struct __align__(16) SmemG {
  union {
    bf16_t stage[3][(BM + BN) * BK];
    float gate[BM * 129];
  };
};

// ---------------------------------------------------------------------------
// Persistent kernel: all 144 LSTM steps, ONE cooperative launch, 256 WGs of
// 512 threads (8 waves = 2/SIMD). Wave grid 2x4, wave-tile 32x32, acc 2x2.
// Staging is per-wave-uniform: every wave stages exactly 3 loads per k-slice
// (1 A-chunk + 2 W-chunks), so counted vmcnt is exact per wave: steady 9,
// tail ladder 9/6/3/0. Depth-4 prefetch over 5 buffers.
//
// Schedule v5: NO in-loop flag polls and NO in-loop vmcnt(0). The K-loop's
// vmcnt counter sees ONLY staging loads (bias hoisted to registers, c-state
// lives in registers, flag loads only in the post-step spin). Per step:
//   K-loop (pure: ladder-waits + barrier + stage + compute)
//   epilogue (gate LDS round-trip, c4 regs, h stores sc0|sc1)
//   vmcnt(0) store drain -> syncthreads -> publish flag (=s+1)
//   enc-next: stage next 4 src+W slices, THEN panel spin (flag RT overlaps
//             the staged loads' L2 latency)
//   dec-next: panel spin, THEN stage next 4 h+W slices (completion covered
//             by next K-loop's ladder)
// Flag semantics: flag>=s+1  =>  that WG's h for step s is MALL-visible.
// Panels (m-rows) are independent; spin reads this panel's 32 flags with one
// vector load (lane i -> flag i), __all(>= s+1).
// ---------------------------------------------------------------------------
__global__ __launch_bounds__(512, 1) void lstm_chain(
    const bf16_t* __restrict__ srcbf,
    const bf16_t* __restrict__ Wcat,
    const bf16_t* __restrict__ Wdec,
    const float* __restrict__ biasE,
    const float* __restrict__ biasD,
    bf16_t* __restrict__ hA,
    bf16_t* __restrict__ hB,
    bf16_t* __restrict__ Hs,
    unsigned* __restrict__ flags)
{
  __shared__ SmemChain sm;
  const int t    = threadIdx.x;
  const int bid  = blockIdx.x;
  const int n0   = (bid & 31) * BN;   // x-fastest: W panels stay L2-resident
  const int m0   = (bid >> 5) * BM;
  const int lane = t & 63;
  const int wv   = t >> 6;            // 0..7
  const int wm   = wv >> 2;           // 0..1 (row block)
  const int wn   = wv & 3;            // 0..3 (col block)
  const int fr   = lane & 15;
  const int fq   = lane >> 4;

  char* ldsbase = (char*)&sm.stage[0][0];

  // ---- staging geometry (uniform: each wave = 1 A-chunk + 2 W-chunks) ----
  const int sgrp = lane >> 3;                        // 0..7 row in group
  const int sw8  = (((lane & 7) ^ sgrp) & 7) * 8;    // swizzled col (elems)
  const int aRowOff = 8 * wv + sgrp;                 // A rows 8w..8w+7
  const int wRowOff = 16 * wv + sgrp;                // W rows 16w..16w+15

  // ---- fragment read offsets (swizzle-aware) ----
  const int swz   = fr & 7;
  const int co0   = ((fq) ^ swz) * 16;
  const int co1   = ((4 + fq) ^ swz) * 16;
  const int arow0 = (wm * 32 + fr) * 128;
  const int arow1 = (wm * 32 + 16 + fr) * 128;
  const int brow  = 8192 + (wn * 32 + fr) * 128;
  const int u0    = n0 >> 2;

  const int panel = m0 >> 6;
  unsigned* flg = flags + panel * 32;     // this panel's 32 producer flags
  unsigned* myf = flg + (n0 >> 7);        // our own flag (BN=128)
  const unsigned* myFlagAddr = flg + (lane & 31);

  // stage one k-slice: 1 A gload + 2 W gloads per wave (3 vmcnt events)
  auto stageSlice = [&](const bf16_t* Ab, int sA, int ka, bool coh,
                        const bf16_t* Wb, int sW2, int kw, int buf) {
    char* lb = ldsbase + buf * BUFB;
    const bf16_t* ap = Ab + (size_t)(m0 + aRowOff) * sA + sw8 + ka;
    if (coh) gload16c(ap, lb + wv * 1024);
    else     gload16 (ap, lb + wv * 1024);
    const bf16_t* wp = Wb + (size_t)(n0 + wRowOff) * sW2 + sw8 + kw;
    gload16(wp, lb + 8192 + wv * 2048);
    gload16(wp + (size_t)8 * sW2, lb + 8192 + wv * 2048 + 1024);
  };

  f32x4 acc[2][2];

  auto compute = [&](int bf) {
    const char* Lb = ldsbase + bf * BUFB;
#pragma unroll
    for (int kk = 0; kk < 2; ++kk) {
      const int co = kk ? co1 : co0;
      bf16x8 av0 = *(const bf16x8*)(Lb + arow0 + co);
      bf16x8 av1 = *(const bf16x8*)(Lb + arow1 + co);
      bf16x8 bv0 = *(const bf16x8*)(Lb + brow + co);
      bf16x8 bv1 = *(const bf16x8*)(Lb + brow + 2048 + co);
      acc[0][0] = __builtin_amdgcn_mfma_f32_16x16x32_bf16(av0, bv0, acc[0][0], 0, 0, 0);
      acc[0][1] = __builtin_amdgcn_mfma_f32_16x16x32_bf16(av0, bv1, acc[0][1], 0, 0, 0);
      acc[1][0] = __builtin_amdgcn_mfma_f32_16x16x32_bf16(av1, bv0, acc[1][0], 0, 0, 0);
      acc[1][1] = __builtin_amdgcn_mfma_f32_16x16x32_bf16(av1, bv1, acc[1][1], 0, 0, 0);
    }
  };

  // Once-per-step panel wait: one vector load covers all 32 panel flags.
  // (Inner vmcnt(0) also completes any loads issued just before the spin,
  // overlapping their latency with the flag round-trip.)
  auto panelSpin = [&](unsigned need) {
    for (;;) {
      unsigned v;
      asm volatile("global_load_dword %0, %1, off sc0 sc1\n\t"
                   "s_waitcnt vmcnt(0)"
                   : "=v"(v) : "v"(myFlagAddr) : "memory");
      if (__all((int)(v >= need))) break;
      __builtin_amdgcn_s_sleep(2);
    }
  };

  // ---- persistent per-thread state ----
  float c4[4] = {0.f, 0.f, 0.f, 0.f};   // LSTM c-state (WG-private mapping)
  float biasE2[2], biasD2[2];           // hoisted epilogue biases
#pragma unroll
  for (int j = 0; j < 2; ++j) {
    int col = n0 + wn * 32 + j * 16 + fr;
    biasE2[j] = biasE[col];
    biasD2[j] = biasD[col];
  }

  const bf16_t* hprev = hA;
  int cb = 0;

  // ---- prologue: stage step-0 slices 0..3 (all src/Wcat), depth 4 ----
  stageSlice(srcbf, DP, 0,      false, Wcat, KENC, 0,      0);
  stageSlice(srcbf, DP, BK,     false, Wcat, KENC, BK,     1);
  stageSlice(srcbf, DP, 2 * BK, false, Wcat, KENC, 2 * BK, 2);
  stageSlice(srcbf, DP, 3 * BK, false, Wcat, KENC, 3 * BK, 3);

#pragma clang loop unroll(disable)
  for (int s = 0; s < 144; ++s) {
    const bool enc = (s <= 120);
    const int  xi  = (s < 120) ? s : 119;
    const bf16_t* Asrc = srcbf + (size_t)xi * B_SZ * DP;
    const int n1 = enc ? (DP / BK) : 0;
    const bf16_t* Wb  = enc ? Wcat : Wdec;
    const int     sWb = enc ? KENC : H_SZ;
    bf16_t* hnext = (s < 120) ? ((s & 1) ? hA : hB)
                              : (Hs + (size_t)(s - 120) * B_SZ * H_SZ);
    const int nTot = n1 + H_SZ / BK;        // 20 enc-structured, 16 dec

    float bias2[2];
#pragma unroll
    for (int j = 0; j < 2; ++j) bias2[j] = enc ? biasE2[j] : biasD2[j];

#pragma unroll
    for (int i = 0; i < 2; ++i)
#pragma unroll
      for (int j = 0; j < 2; ++j) acc[i][j] = (f32x4){0.f, 0.f, 0.f, 0.f};

    // ---- pure K-loop: ladder-wait + barrier + stage + compute ----
    for (int it = 0; it < nTot; ++it) {
      const int rem = nTot - it;
      if (rem >= 4)
        asm volatile("s_waitcnt vmcnt(9)" ::: "memory");
      else if (rem == 3)
        asm volatile("s_waitcnt vmcnt(6)" ::: "memory");
      else if (rem == 2)
        asm volatile("s_waitcnt vmcnt(3)" ::: "memory");
      else
        asm volatile("s_waitcnt vmcnt(0)" ::: "memory");
      __builtin_amdgcn_s_barrier();

      const int j4 = it + 4;
      if (j4 < nTot) {
        int sbuf = cb + 4; if (sbuf >= NBUF) sbuf -= NBUF;
        if (j4 < n1) stageSlice(Asrc, DP, j4 * BK, false, Wb, sWb, j4 * BK, sbuf);
        else         stageSlice(hprev, H_SZ, (j4 - n1) * BK, true, Wb, sWb, j4 * BK, sbuf);
      }

      compute(cb);
      cb = (cb == NBUF - 1) ? 0 : cb + 1;
    }

    // ---- LSTM cell epilogue (gate region disjoint from staging buffers) ----
#pragma unroll
    for (int i = 0; i < 2; ++i)
#pragma unroll
      for (int j = 0; j < 2; ++j)
#pragma unroll
        for (int v = 0; v < 4; ++v) {
          int row = wm * 32 + i * 16 + fq * 4 + v;
          int col = wn * 32 + j * 16 + fr;
          sm.gate[row * 132 + col] = acc[i][j][v] + bias2[j];
        }
    __syncthreads();
#pragma unroll
    for (int itc = 0; itc < 4; ++itc) {
      int ci  = itc * 512 + t;
      int brw = ci >> 5;   // 0..63 local batch row
      int ju  = ci & 31;   // 0..31 local unit
      f32x4 g = *(const f32x4*)&sm.gate[brw * 132 + ju * 4];  // conflict-free
      float iv = fsigmoid(g[0]);
      float fv = fsigmoid(g[1]);
      float gv = ftanh(g[2]);
      float ov = fsigmoid(g[3]);
      float cn = fv * c4[itc] + iv * gv;     // c-state in registers
      c4[itc] = cn;
      bf16_t hb = (bf16_t)(ov * ftanh(cn));
      uint32_t hv32 = (uint32_t)__builtin_bit_cast(uint16_t, hb);
      size_t cix = (size_t)(m0 + brw) * H_SZ + (u0 + ju);
      asm volatile("global_store_short %0, %1, off sc0 sc1"
                   :: "v"((uint16_t*)&hnext[cix]), "v"(hv32) : "memory");
    }
    // per-wave store drain, then barrier, then publish our flag:
    // flag visible at MALL => our h slice visible at MALL.
    asm volatile("s_waitcnt vmcnt(0)" ::: "memory");
    __syncthreads();
    if (t == 0) {
      unsigned fv2 = (unsigned)(s + 1);
      asm volatile("global_store_dword %0, %1, off sc0 sc1"
                   :: "v"(myf), "v"(fv2) : "memory");
    }

    // ---- post-step: stage next step's slices 0..3 + panel spin ----
    if (s < 143) {
      const bool nxtEnc = (s + 1 <= 120);
      if (nxtEnc) {
        // src+W slices: no h dependency -> stage first, spin second (flag RT
        // overlaps the staged loads' L2 latency; spin leaves vmcnt=0).
        const bf16_t* nxtA = srcbf + (size_t)((s + 1 < 120) ? (s + 1) : 119) * B_SZ * DP;
        int b = cb;
#pragma unroll
        for (int q = 0; q < 4; ++q) {
          stageSlice(nxtA, DP, q * BK, false, Wcat, KENC, q * BK, b);
          b = (b == NBUF - 1) ? 0 : b + 1;
        }
        panelSpin((unsigned)(s + 1));
      } else {
        // h slices: spin first, then stage; completion covered by next
        // K-loop's vmcnt ladder.
        panelSpin((unsigned)(s + 1));
        int b = cb;
#pragma unroll
        for (int q = 0; q < 4; ++q) {
          stageSlice(hnext, H_SZ, q * BK, true, Wdec, H_SZ, q * BK, b);
          b = (b == NBUF - 1) ? 0 : b + 1;
        }
      }
    }

    hprev = hnext;
  }
}

// ---------------------------------------------------------------------------
// Standalone GEMM (EPI=2 W_dec build, EPI=3 final projection) — baseline.
// ---------------------------------------------------------------------------
template <int EPI>
__global__ __launch_bounds__(256, 1) void gemm_step(
    const bf16_t* __restrict__ A1, int sA1, int n1,
    const bf16_t* __restrict__ A2, int sA2, int n2,
    const bf16_t* __restrict__ W, int sW,
    const float* __restrict__ bias,
    float* __restrict__ cbuf, bf16_t* __restrict__ hout,
    const float* __restrict__ addm, bf16_t* __restrict__ outb,
    float* __restrict__ outf)
{
  __shared__ SmemG sm;
  const int t    = threadIdx.x;
  const int m0   = blockIdx.y * BM;
  const int n0   = blockIdx.x * BN;
  const int lane = t & 63;
  const int wv   = t >> 6;
  const int wm   = wv >> 1, wn = wv & 1;
  const int fr   = lane & 15;
  const int fq   = lane >> 4;

  f32x4 acc[2][4] = {};

  float bias4[4];
  if (EPI == 1 || EPI == 3) {
#pragma unroll
    for (int j = 0; j < 4; ++j) {
      int col = n0 + wn * 64 + j * 16 + fr;
      bias4[j] = (EPI == 3 && col >= D_SZ) ? 0.f : bias[col];
    }
  }

  const int r0   = t >> 3;
  const int gcol = (((t & 7) ^ (r0 & 7)) * 8);
  char* ldsbase  = (char*)&sm.stage[0][0];
  const int wofs = wv * 1024;

  const bf16_t* pA1 = A1 ? A1 : A2;
  const bf16_t* pA2 = A2 ? A2 : A1;
  const bf16_t* a1p0 = pA1 + (size_t)(m0 + r0) * sA1 + gcol;
  const bf16_t* a1p1 = pA1 + (size_t)(m0 + r0 + 32) * sA1 + gcol;
  const bf16_t* a2p0 = pA2 + (size_t)(m0 + r0) * sA2 + gcol;
  const bf16_t* a2p1 = pA2 + (size_t)(m0 + r0 + 32) * sA2 + gcol;
  const bf16_t* wp0  = W + (size_t)(n0 + r0) * sW + gcol;
  const bf16_t* wp1  = W + (size_t)(n0 + r0 + 32) * sW + gcol;
  const bf16_t* wp2  = W + (size_t)(n0 + r0 + 64) * sW + gcol;
  const bf16_t* wp3  = W + (size_t)(n0 + r0 + 96) * sW + gcol;

  const int nTot = n1 + n2;

  auto stage = [&](int j, int bf) {
    char* Ab = ldsbase + bf * BUFB + wofs;
    char* Bb = ldsbase + bf * BUFB + 8192 + wofs;
    const int k = j * BK;
    const bf16_t *a0, *a1;
    if (j < n1) { a0 = a1p0 + k; a1 = a1p1 + k; }
    else { const int k2 = k - n1 * BK; a0 = a2p0 + k2; a1 = a2p1 + k2; }
    gload16(a0, Ab);
    gload16(a1, Ab + 4096);
    gload16(wp0 + k, Bb);
    gload16(wp1 + k, Bb + 4096);
    gload16(wp2 + k, Bb + 8192);
    gload16(wp3 + k, Bb + 12288);
  };

  const int swz  = fr & 7;
  const int co0  = ((fq) ^ swz) * 16;
  const int co1  = ((4 + fq) ^ swz) * 16;
  const int arow0 = (wm * 32 + fr) * 128;
  const int arow1 = (wm * 32 + 16 + fr) * 128;
  const int brow  = (wn * 64 + fr) * 128;

  auto compute = [&](int bf) {
    const char* Ab = ldsbase + bf * BUFB;
    const char* Bb = Ab + 8192;
#pragma unroll
    for (int kk = 0; kk < 2; ++kk) {
      const int co = kk ? co1 : co0;
      bf16x8 av0 = *(const bf16x8*)(Ab + arow0 + co);
      bf16x8 av1 = *(const bf16x8*)(Ab + arow1 + co);
      bf16x8 bv[4];
#pragma unroll
      for (int j = 0; j < 4; ++j)
        bv[j] = *(const bf16x8*)(Bb + brow + j * 2048 + co);
#pragma unroll
      for (int j = 0; j < 4; ++j) {
        acc[0][j] = __builtin_amdgcn_mfma_f32_16x16x32_bf16(av0, bv[j], acc[0][j], 0, 0, 0);
        acc[1][j] = __builtin_amdgcn_mfma_f32_16x16x32_bf16(av1, bv[j], acc[1][j], 0, 0, 0);
      }
    }
  };

  stage(0, 0);
  if (nTot > 1) stage(1, 1);
  int cb = 0, sb = 2;
  for (int it = 0; it < nTot; ++it) {
    if (it == nTot - 1) {
      asm volatile("s_waitcnt vmcnt(0)" ::: "memory");
    } else {
      asm volatile("s_waitcnt vmcnt(6)" ::: "memory");
    }
    __builtin_amdgcn_s_barrier();
    if (it + 2 < nTot) stage(it + 2, sb);
    sb = (sb == 2) ? 0 : sb + 1;
    compute(cb);
    cb = (cb == 2) ? 0 : cb + 1;
  }
  __syncthreads();

  if (EPI == 1) {
#pragma unroll
    for (int i = 0; i < 2; ++i)
#pragma unroll
      for (int j = 0; j < 4; ++j)
#pragma unroll
        for (int v = 0; v < 4; ++v) {
          int row = wm * 32 + i * 16 + fq * 4 + v;
          int col = wn * 64 + j * 16 + fr;
          sm.gate[row * 129 + col] = acc[i][j][v] + bias4[j];
        }
    __syncthreads();
    const int u0 = n0 >> 2;
#pragma unroll
    for (int itc = 0; itc < 8; ++itc) {
      int ci = itc * 256 + t;
      int brw = ci >> 5;
      int ju  = ci & 31;
      const float* gp = &sm.gate[brw * 129 + ju * 4];
      float iv = fsigmoid(gp[0]);
      float fv = fsigmoid(gp[1]);
      float gv = ftanh(gp[2]);
      float ov = fsigmoid(gp[3]);
      size_t cix = (size_t)(m0 + brw) * H_SZ + (u0 + ju);
      float cn = fv * cbuf[cix] + iv * gv;
      cbuf[cix] = cn;
      hout[cix] = (bf16_t)(ov * ftanh(cn));
    }
  }

  if (EPI == 2) {
#pragma unroll
    for (int i = 0; i < 2; ++i)
#pragma unroll
      for (int j = 0; j < 4; ++j)
#pragma unroll
        for (int v = 0; v < 4; ++v) {
          int gr = m0 + wm * 32 + i * 16 + fq * 4 + v;
          int gc = n0 + wn * 64 + j * 16 + fr;
          int orig = (gr & 3) * H_SZ + (gr >> 2);
          float val = acc[i][j][v] + addm[(size_t)orig * H_SZ + gc];
          outb[(size_t)gr * H_SZ + gc] = (bf16_t)val;
        }
  }

  if (EPI == 3) {
#pragma unroll
    for (int i = 0; i < 2; ++i)
#pragma unroll
      for (int j = 0; j < 4; ++j)
#pragma unroll
        for (int v = 0; v < 4; ++v) {
          int m = m0 + wm * 32 + i * 16 + fq * 4 + v;
          int n = n0 + wn * 64 + j * 16 + fr;
          if (n < D_SZ) {
            int ts = m >> 9;
            int bb = m & 511;
            outf[((size_t)bb * TMAX + ts) * D_SZ + n] = acc[i][j][v] + bias4[j];
          }
        }
  }
}

// src (B,S,D) fp32 -> srcbf (S,B,DP) bf16, zero-padded d>=216
__global__ void k_convert_src(const float* __restrict__ src, bf16_t* __restrict__ dst) {
  int idx = blockIdx.x * 256 + threadIdx.x;
  int total = S_SZ * B_SZ * DP;
  if (idx >= total) return;
  int d = idx % DP;
  int r = idx / DP;
  int b = r % B_SZ;
  int tt = r / B_SZ;
  float v = (d < D_SZ) ? src[((size_t)b * S_SZ + tt) * D_SZ + d] : 0.f;
  dst[idx] = (bf16_t)v;
}

__global__ void k_build_wcat(const float* __restrict__ Wih, const float* __restrict__ Whh,
                             bf16_t* __restrict__ Wcat) {
  int idx = blockIdx.x * 256 + threadIdx.x;
  if (idx >= NG * KENC) return;
  int k = idx % KENC;
  int r = idx / KENC;
  int o = (r & 3) * H_SZ + (r >> 2);
  float v;
  if (k < D_SZ)      v = Wih[(size_t)o * D_SZ + k];
  else if (k < DP)   v = 0.f;
  else               v = Whh[(size_t)o * H_SZ + (k - DP)];
  Wcat[idx] = (bf16_t)v;
}

__global__ void k_build_wout(const float* __restrict__ Wout, bf16_t* __restrict__ WoutB,
                             bf16_t* __restrict__ WoutT) {
  int idx = blockIdx.x * 256 + threadIdx.x;
  if (idx < 256 * H_SZ) {
    int h = idx % H_SZ, d = idx / H_SZ;
    WoutB[idx] = (bf16_t)((d < D_SZ) ? Wout[(size_t)d * H_SZ + h] : 0.f);
  }
  if (idx < H_SZ * DP) {
    int d = idx % DP, h = idx / DP;
    WoutT[idx] = (bf16_t)((d < D_SZ) ? Wout[(size_t)d * H_SZ + h] : 0.f);
  }
}

__global__ void k_build_bias(const float* __restrict__ bih, const float* __restrict__ bhh,
                             const float* __restrict__ Wih, const float* __restrict__ bout,
                             float* __restrict__ biasE, float* __restrict__ biasD) {
  int r = blockIdx.x * 256 + threadIdx.x;
  if (r >= NG) return;
  int o = (r & 3) * H_SZ + (r >> 2);
  float be = bih[o] + bhh[o];
  biasE[r] = be;
  float s = 0.f;
  const float* wr = Wih + (size_t)o * D_SZ;
  for (int d = 0; d < D_SZ; ++d) s += wr[d] * bout[d];
  biasD[r] = be + s;
}

extern "C" void kernel_launch(void* const* d_in, const int* in_sizes, int n_in,
                              void* d_out, int out_size, void* d_ws, size_t ws_size,
                              hipStream_t stream) {
  const float* src  = (const float*)d_in[0];
  const float* Wih  = (const float*)d_in[1];
  const float* Whh  = (const float*)d_in[2];
  const float* bih  = (const float*)d_in[3];
  const float* bhh  = (const float*)d_in[4];
  const float* Wout = (const float*)d_in[5];
  const float* bout = (const float*)d_in[6];

  char* ws = (char*)d_ws;
  size_t off = 0;
  auto alloc = [&](size_t bytes) {
    void* p = ws + off;
    off = (off + bytes + 255) & ~(size_t)255;
    return p;
  };
  bf16_t* srcbf = (bf16_t*)alloc((size_t)S_SZ * B_SZ * DP * 2);
  bf16_t* Wcat  = (bf16_t*)alloc((size_t)NG * KENC * 2);
  bf16_t* Wdec  = (bf16_t*)alloc((size_t)NG * H_SZ * 2);
  bf16_t* WoutB = (bf16_t*)alloc((size_t)256 * H_SZ * 2);
  bf16_t* WoutT = (bf16_t*)alloc((size_t)H_SZ * DP * 2);
  float*  biasE = (float*)alloc((size_t)NG * 4);
  float*  biasD = (float*)alloc((size_t)NG * 4);
  float*  cbuf  = (float*)alloc((size_t)B_SZ * H_SZ * 4);
  bf16_t* hP0   = (bf16_t*)alloc((size_t)B_SZ * H_SZ * 2);
  bf16_t* hP1   = (bf16_t*)alloc((size_t)B_SZ * H_SZ * 2);
  bf16_t* Hs    = (bf16_t*)alloc((size_t)TMAX * B_SZ * H_SZ * 2);
  unsigned* flags = (unsigned*)alloc(1024);

  hipMemsetAsync(hP0, 0, (size_t)B_SZ * H_SZ * 2, stream);
  hipMemsetAsync(flags, 0, 1024, stream);

  k_convert_src<<<(S_SZ * B_SZ * DP + 255) / 256, 256, 0, stream>>>(src, srcbf);
  k_build_wcat<<<(NG * KENC + 255) / 256, 256, 0, stream>>>(Wih, Whh, Wcat);
  k_build_wout<<<1024, 256, 0, stream>>>(Wout, WoutB, WoutT);
  k_build_bias<<<(NG + 255) / 256, 256, 0, stream>>>(bih, bhh, Wih, bout, biasE, biasD);

  // W_dec = W_hh(reordered) + W_ih(reordered) @ W_out   (M=4096, N=1024, K=256)
  gemm_step<2><<<dim3(H_SZ / BN, NG / BM), 256, 0, stream>>>(
      Wcat, KENC, DP / BK, nullptr, 0, 0, WoutT, DP,
      nullptr, nullptr, nullptr, Whh, Wdec, nullptr);

  // All 144 sequential steps: one persistent cooperative kernel, 512 threads.
  {
    const bf16_t* a_src = srcbf;
    const bf16_t* a_wc  = Wcat;
    const bf16_t* a_wd  = Wdec;
    const float*  a_bE  = biasE;
    const float*  a_bD  = biasD;
    bf16_t*       a_hA  = hP0;
    bf16_t*       a_hB  = hP1;
    bf16_t*       a_Hs  = Hs;
    unsigned*     a_fl  = flags;
    void* kargs[] = {&a_src, &a_wc, &a_wd, &a_bE, &a_bD,
                     &a_hA, &a_hB, &a_Hs, &a_fl};
    hipLaunchCooperativeKernel((void*)lstm_chain, dim3(256), dim3(512),
                               kargs, 0, stream);
  }

  // Final projection: Y(12288 x 216) = Hs(12288 x 1024) @ W_out^T + b_out
  gemm_step<3><<<dim3(2, (TMAX * B_SZ) / BM), 256, 0, stream>>>(
      nullptr, 0, 0, Hs, H_SZ, H_SZ / BK, WoutB, H_SZ,
      bout, nullptr, nullptr, nullptr, nullptr, (float*)d_out);
}

// Round 6
// 1719.701 us; speedup vs baseline: 1.4853x; 1.0066x over previous
//
#include <hip/hip_runtime.h>
#include <cstdint>
#include <cstddef>

// Problem constants
#define B_SZ 512
#define S_SZ 120
#define D_SZ 216
#define H_SZ 1024
#define NG   4096     // 4*H
#define DP   256      // D padded to multiple of BK
#define KENC 1280     // DP + H
#define TMAX 24

// GEMM tile config
#define BM 64
#define BN 128
#define BK 64
#define NBUF 6        // lstm_chain staging buffers (6-slice window, k-split pairs)

using bf16_t = __bf16;
using bf16x8 = __attribute__((ext_vector_type(8))) __bf16;
using f32x4  = __attribute__((ext_vector_type(4))) float;

__device__ __forceinline__ void gload16(const void* g, void* l) {
  __builtin_amdgcn_global_load_lds(
      (const __attribute__((address_space(1))) void*)g,
      (__attribute__((address_space(3))) void*)l, 16, 0, 0);
}
// Coherent variant for h (cross-XCD producer): sc0|sc1 bypasses potentially
// stale L1/L2 and reads from the device coherence point (MALL).
__device__ __forceinline__ void gload16c(const void* g, void* l) {
  __builtin_amdgcn_global_load_lds(
      (const __attribute__((address_space(1))) void*)g,
      (__attribute__((address_space(3))) void*)l, 16, 0, 0x11);
}

__device__ __forceinline__ float fsigmoid(float x) {
  x = fminf(fmaxf(x, -30.f), 30.f);
  return 1.f / (1.f + __expf(-x));
}
__device__ __forceinline__ float ftanh(float x) {
  x = fminf(fmaxf(x, -15.f), 15.f);
  float e = __expf(2.f * x);
  return (e - 1.f) / (e + 1.f);
}

#define BUFB 24576

// lstm_chain LDS: SIX staging buffers (A 64x64 bf16 = 8KB + B 128x64 bf16 =
// 16KB each) = 144KB. The gate/exchange region (64 x 132 f32 = 33KB) ALIASES
// the two stage buffers that are provably free at step end (the buffers of
// slices nTot-2/nTot-1, fully consumed before the epilogue's first barrier,
// and not targeted by the post-step staging of next-step slices 0..3).
struct __align__(16) SmemChain {
  bf16_t stage[NBUF][(BM + BN) * BK];  // 147456 B < 160 KiB
};

// gemm_step LDS (original baseline layout, union: 73728 B)
struct __align__(16) SmemG {
  union {
    bf16_t stage[3][(BM + BN) * BK];
    float gate[BM * 129];
  };
};

// ---------------------------------------------------------------------------
// Persistent kernel v6: all 144 LSTM steps, ONE cooperative launch, 256 WGs
// of 512 threads (8 waves = 2/SIMD).
//
// K-SPLIT STRUCTURE (the LDS-bandwidth fix): waves form 2 k-groups (kg=wv&1)
// x 4 tile-waves (wt=wv>>1, 2x2 grid of 32x64 tiles, acc[2][4]). Group 0
// computes even k-slices, group 1 odd ones, concurrently after one shared
// barrier per PAIR of slices. Per slice the 4 consuming waves read
// 4 A-frags + 8 B-frags = 12KB each -> 48KB/slice (vs 64KB for the 2x4
// 32x32 grid), and barriers/ladder-waits halve. Each wave still stages 3
// loads per slice (1 A + 2 W chunks), so the per-wave vmcnt ladder is:
// steady (g0,g1)=(9,6) [3 resp. 2 newer slices in flight], last pair (3,0).
// Window: compute pair p while staging slices 2p+4,2p+5 -> 6 buffers.
//
// Epilogue: __syncthreads (drains vmcnt: pending stage writes to the gate-
// aliased buffers!), g0 writes acc+bias into gate LDS (stride 132, conflict-
// free), barrier, g1 read-add-writes its K-partial, barrier, all 512 threads
// run the cell pass (c-state in registers, h stores sc0|sc1 to MALL), drain,
// publish per-WG monotone flag, then post-step staging + once-per-step panel
// spin (enc: stage src slices then spin; dec: spin then stage h slices).
// Flag semantics: flag>=s+1 => that WG's h for step s is MALL-visible.
// ---------------------------------------------------------------------------
__global__ __launch_bounds__(512, 1) void lstm_chain(
    const bf16_t* __restrict__ srcbf,
    const bf16_t* __restrict__ Wcat,
    const bf16_t* __restrict__ Wdec,
    const float* __restrict__ biasE,
    const float* __restrict__ biasD,
    bf16_t* __restrict__ hA,
    bf16_t* __restrict__ hB,
    bf16_t* __restrict__ Hs,
    unsigned* __restrict__ flags)
{
  __shared__ SmemChain sm;
  const int t    = threadIdx.x;
  const int bid  = blockIdx.x;
  const int n0   = (bid & 31) * BN;   // x-fastest: W panels stay L2-resident
  const int m0   = (bid >> 5) * BM;
  const int lane = t & 63;
  const int wv   = t >> 6;            // 0..7
  const int kg   = wv & 1;            // k-group (0: even slices, 1: odd)
  const int wt   = wv >> 1;           // 0..3 tile wave
  const int tm   = wt >> 1;           // 0..1 row block (32 rows)
  const int tn   = wt & 1;            // 0..1 col block (64 cols)
  const int fr   = lane & 15;
  const int fq   = lane >> 4;

  char* ldsbase = (char*)&sm.stage[0][0];

  // ---- staging geometry (uniform: each wave = 1 A-chunk + 2 W-chunks) ----
  const int sgrp = lane >> 3;                        // 0..7 row in group
  const int sw8  = (((lane & 7) ^ sgrp) & 7) * 8;    // swizzled col (elems)
  const int aRowOff = 8 * wv + sgrp;                 // A rows 8w..8w+7
  const int wRowOff = 16 * wv + sgrp;                // W rows 16w..16w+15

  // ---- fragment read offsets (swizzle-aware, conflict-free) ----
  const int swz   = fr & 7;
  const int co0   = ((fq) ^ swz) * 16;
  const int co1   = ((4 + fq) ^ swz) * 16;
  const int arow0 = (tm * 32 + fr) * 128;
  const int arow1 = (tm * 32 + 16 + fr) * 128;
  const int brow  = 8192 + (tn * 64 + fr) * 128;
  const int u0    = n0 >> 2;

  const int panel = m0 >> 6;
  unsigned* flg = flags + panel * 32;     // this panel's 32 producer flags
  unsigned* myf = flg + (n0 >> 7);        // our own flag (BN=128)
  const unsigned* myFlagAddr = flg + (lane & 31);

  // stage one k-slice: 1 A gload + 2 W gloads per wave (3 vmcnt events)
  auto stageSlice = [&](const bf16_t* Ab, int sA, int ka, bool coh,
                        const bf16_t* Wb, int sW2, int kw, int buf) {
    char* lb = ldsbase + buf * BUFB;
    const bf16_t* ap = Ab + (size_t)(m0 + aRowOff) * sA + sw8 + ka;
    if (coh) gload16c(ap, lb + wv * 1024);
    else     gload16 (ap, lb + wv * 1024);
    const bf16_t* wp = Wb + (size_t)(n0 + wRowOff) * sW2 + sw8 + kw;
    gload16(wp, lb + 8192 + wv * 2048);
    gload16(wp + (size_t)8 * sW2, lb + 8192 + wv * 2048 + 1024);
  };

  f32x4 acc[2][4];

  // 32x64 wave tile: per kk reads 2 A-frags + 4 B-frags, 8 MFMA (16/slice).
  auto compute = [&](int bf) {
    const char* Lb = ldsbase + bf * BUFB;
#pragma unroll
    for (int kk = 0; kk < 2; ++kk) {
      const int co = kk ? co1 : co0;
      bf16x8 av0 = *(const bf16x8*)(Lb + arow0 + co);
      bf16x8 av1 = *(const bf16x8*)(Lb + arow1 + co);
      bf16x8 bv[4];
#pragma unroll
      for (int j = 0; j < 4; ++j)
        bv[j] = *(const bf16x8*)(Lb + brow + j * 2048 + co);
#pragma unroll
      for (int j = 0; j < 4; ++j) {
        acc[0][j] = __builtin_amdgcn_mfma_f32_16x16x32_bf16(av0, bv[j], acc[0][j], 0, 0, 0);
        acc[1][j] = __builtin_amdgcn_mfma_f32_16x16x32_bf16(av1, bv[j], acc[1][j], 0, 0, 0);
      }
    }
  };

  // Once-per-step panel wait: one vector load covers all 32 panel flags.
  auto panelSpin = [&](unsigned need) {
    for (;;) {
      unsigned v;
      asm volatile("global_load_dword %0, %1, off sc0 sc1\n\t"
                   "s_waitcnt vmcnt(0)"
                   : "=v"(v) : "v"(myFlagAddr) : "memory");
      if (__all((int)(v >= need))) break;
      __builtin_amdgcn_s_sleep(2);
    }
  };

  // ---- persistent per-thread state ----
  float c4[4] = {0.f, 0.f, 0.f, 0.f};   // LSTM c-state (WG-private mapping)
  float biasE4[4], biasD4[4];           // hoisted epilogue biases
#pragma unroll
  for (int j = 0; j < 4; ++j) {
    int col = n0 + tn * 64 + j * 16 + fr;
    biasE4[j] = biasE[col];
    biasD4[j] = biasD[col];
  }

  const bf16_t* hprev = hA;
  int b0 = 0;   // rolling buffer base: slice j of current step -> buf (b0+j)%6

  // ---- prologue: stage step-0 slices 0..3 (all src/Wcat) into bufs 0..3 ----
  stageSlice(srcbf, DP, 0,      false, Wcat, KENC, 0,      0);
  stageSlice(srcbf, DP, BK,     false, Wcat, KENC, BK,     1);
  stageSlice(srcbf, DP, 2 * BK, false, Wcat, KENC, 2 * BK, 2);
  stageSlice(srcbf, DP, 3 * BK, false, Wcat, KENC, 3 * BK, 3);

#pragma clang loop unroll(disable)
  for (int s = 0; s < 144; ++s) {
    const bool enc = (s <= 120);
    const int n1 = enc ? (DP / BK) : 0;
    const bf16_t* Wb  = enc ? Wcat : Wdec;
    const int     sWb = enc ? KENC : H_SZ;
    bf16_t* hnext = (s < 120) ? ((s & 1) ? hA : hB)
                              : (Hs + (size_t)(s - 120) * B_SZ * H_SZ);
    const int nTot   = n1 + H_SZ / BK;      // 20 enc-structured, 16 dec
    const int npairs = nTot >> 1;           // 10 / 8

    float bias4[4];
#pragma unroll
    for (int j = 0; j < 4; ++j) bias4[j] = enc ? biasE4[j] : biasD4[j];

#pragma unroll
    for (int i = 0; i < 2; ++i)
#pragma unroll
      for (int j = 0; j < 4; ++j) acc[i][j] = (f32x4){0.f, 0.f, 0.f, 0.f};

    // my compute buffer (slice 2p+kg) and the stage cursor (slice 4)
    int cbm = b0 + kg;          if (cbm >= NBUF) cbm -= NBUF;
    int sb  = b0 + 4;           if (sb  >= NBUF) sb  -= NBUF;

    // ---- K-loop over slice PAIRS: one wait + one barrier per pair ----
    for (int p = 0; p < npairs; ++p) {
      if (p < npairs - 1) {
        if (kg == 0) asm volatile("s_waitcnt vmcnt(9)" ::: "memory");
        else         asm volatile("s_waitcnt vmcnt(6)" ::: "memory");
      } else {
        if (kg == 0) asm volatile("s_waitcnt vmcnt(3)" ::: "memory");
        else         asm volatile("s_waitcnt vmcnt(0)" ::: "memory");
      }
      __builtin_amdgcn_s_barrier();

      const int js = 2 * p + 4;            // stage targets: js, js+1
      if (js < nTot) {
        // in-loop slices are ALWAYS h-sourced (src slices 0..3 staged at
        // step boundaries): A offset (js-n1)*BK into hprev, coherent.
        stageSlice(hprev, H_SZ, (js - n1) * BK, true, Wb, sWb, js * BK, sb);
        int sb2 = sb + 1; if (sb2 >= NBUF) sb2 -= NBUF;
        stageSlice(hprev, H_SZ, (js + 1 - n1) * BK, true, Wb, sWb, (js + 1) * BK, sb2);
        sb = sb2 + 1; if (sb >= NBUF) sb -= NBUF;
      }

      compute(cbm);
      cbm += 2; if (cbm >= NBUF) cbm -= NBUF;
    }

    // ---- epilogue: cross-group sum + LSTM cell ----
    // gate region aliases the two buffers of slices nTot-2/nTot-1 (free now;
    // not targeted by post-step staging). __syncthreads drains vmcnt so no
    // in-flight global_load_lds can land in the aliased buffers afterwards.
    const int gbuf = (b0 + nTot + 4) % NBUF;     // always != 5 for our nTot seq
    float* gate = (float*)(ldsbase + gbuf * BUFB);
    __syncthreads();

    if (kg == 0) {
#pragma unroll
      for (int i = 0; i < 2; ++i)
#pragma unroll
        for (int j = 0; j < 4; ++j)
#pragma unroll
          for (int v = 0; v < 4; ++v) {
            int row = tm * 32 + i * 16 + fq * 4 + v;
            int col = tn * 64 + j * 16 + fr;
            gate[row * 132 + col] = acc[i][j][v] + bias4[j];
          }
    }
    __syncthreads();
    if (kg == 1) {
#pragma unroll
      for (int i = 0; i < 2; ++i)
#pragma unroll
        for (int j = 0; j < 4; ++j)
#pragma unroll
          for (int v = 0; v < 4; ++v) {
            int row = tm * 32 + i * 16 + fq * 4 + v;
            int col = tn * 64 + j * 16 + fr;
            gate[row * 132 + col] += acc[i][j][v];
          }
    }
    __syncthreads();

#pragma unroll
    for (int itc = 0; itc < 4; ++itc) {
      int ci  = itc * 512 + t;
      int brw = ci >> 5;   // 0..63 local batch row
      int ju  = ci & 31;   // 0..31 local unit
      f32x4 g = *(const f32x4*)&gate[brw * 132 + ju * 4];  // conflict-free
      float iv = fsigmoid(g[0]);
      float fv = fsigmoid(g[1]);
      float gv = ftanh(g[2]);
      float ov = fsigmoid(g[3]);
      float cn = fv * c4[itc] + iv * gv;     // c-state in registers
      c4[itc] = cn;
      bf16_t hb = (bf16_t)(ov * ftanh(cn));
      uint32_t hv32 = (uint32_t)__builtin_bit_cast(uint16_t, hb);
      size_t cix = (size_t)(m0 + brw) * H_SZ + (u0 + ju);
      asm volatile("global_store_short %0, %1, off sc0 sc1"
                   :: "v"((uint16_t*)&hnext[cix]), "v"(hv32) : "memory");
    }
    // per-wave store drain, then barrier, then publish our flag:
    // flag visible at MALL => our h slice visible at MALL.
    asm volatile("s_waitcnt vmcnt(0)" ::: "memory");
    __syncthreads();
    if (t == 0) {
      unsigned fv2 = (unsigned)(s + 1);
      asm volatile("global_store_dword %0, %1, off sc0 sc1"
                   :: "v"(myf), "v"(fv2) : "memory");
    }

    // ---- post-step: stage next step's slices 0..3 + panel spin ----
    int nb0 = b0 + (nTot - ((nTot / NBUF) * NBUF));  // (b0 + nTot) mod 6
    if (nb0 >= NBUF) nb0 -= NBUF;
    if (s < 143) {
      const bool nxtEnc = (s + 1 <= 120);
      if (nxtEnc) {
        // src+W slices: no h dependency -> stage first, spin second (flag RT
        // overlaps the staged loads' L2 latency; spin leaves vmcnt=0).
        const bf16_t* nxtA = srcbf + (size_t)((s + 1 < 120) ? (s + 1) : 119) * B_SZ * DP;
        int b = nb0;
#pragma unroll
        for (int q = 0; q < 4; ++q) {
          stageSlice(nxtA, DP, q * BK, false, Wcat, KENC, q * BK, b);
          b = (b == NBUF - 1) ? 0 : b + 1;
        }
        panelSpin((unsigned)(s + 1));
      } else {
        // h slices: spin first, then stage; completion covered by next
        // K-loop's vmcnt ladder.
        panelSpin((unsigned)(s + 1));
        int b = nb0;
#pragma unroll
        for (int q = 0; q < 4; ++q) {
          stageSlice(hnext, H_SZ, q * BK, true, Wdec, H_SZ, q * BK, b);
          b = (b == NBUF - 1) ? 0 : b + 1;
        }
      }
    }

    b0 = nb0;
    hprev = hnext;
  }
}

// ---------------------------------------------------------------------------
// Standalone GEMM (EPI=2 W_dec build, EPI=3 final projection) — baseline.
// ---------------------------------------------------------------------------
template <int EPI>
__global__ __launch_bounds__(256, 1) void gemm_step(
    const bf16_t* __restrict__ A1, int sA1, int n1,
    const bf16_t* __restrict__ A2, int sA2, int n2,
    const bf16_t* __restrict__ W, int sW,
    const float* __restrict__ bias,
    float* __restrict__ cbuf, bf16_t* __restrict__ hout,
    const float* __restrict__ addm, bf16_t* __restrict__ outb,
    float* __restrict__ outf)
{
  __shared__ SmemG sm;
  const int t    = threadIdx.x;
  const int m0   = blockIdx.y * BM;
  const int n0   = blockIdx.x * BN;
  const int lane = t & 63;
  const int wv   = t >> 6;
  const int wm   = wv >> 1, wn = wv & 1;
  const int fr   = lane & 15;
  const int fq   = lane >> 4;

  f32x4 acc[2][4] = {};

  float bias4[4];
  if (EPI == 1 || EPI == 3) {
#pragma unroll
    for (int j = 0; j < 4; ++j) {
      int col = n0 + wn * 64 + j * 16 + fr;
      bias4[j] = (EPI == 3 && col >= D_SZ) ? 0.f : bias[col];
    }
  }

  const int r0   = t >> 3;
  const int gcol = (((t & 7) ^ (r0 & 7)) * 8);
  char* ldsbase  = (char*)&sm.stage[0][0];
  const int wofs = wv * 1024;

  const bf16_t* pA1 = A1 ? A1 : A2;
  const bf16_t* pA2 = A2 ? A2 : A1;
  const bf16_t* a1p0 = pA1 + (size_t)(m0 + r0) * sA1 + gcol;
  const bf16_t* a1p1 = pA1 + (size_t)(m0 + r0 + 32) * sA1 + gcol;
  const bf16_t* a2p0 = pA2 + (size_t)(m0 + r0) * sA2 + gcol;
  const bf16_t* a2p1 = pA2 + (size_t)(m0 + r0 + 32) * sA2 + gcol;
  const bf16_t* wp0  = W + (size_t)(n0 + r0) * sW + gcol;
  const bf16_t* wp1  = W + (size_t)(n0 + r0 + 32) * sW + gcol;
  const bf16_t* wp2  = W + (size_t)(n0 + r0 + 64) * sW + gcol;
  const bf16_t* wp3  = W + (size_t)(n0 + r0 + 96) * sW + gcol;

  const int nTot = n1 + n2;

  auto stage = [&](int j, int bf) {
    char* Ab = ldsbase + bf * BUFB + wofs;
    char* Bb = ldsbase + bf * BUFB + 8192 + wofs;
    const int k = j * BK;
    const bf16_t *a0, *a1;
    if (j < n1) { a0 = a1p0 + k; a1 = a1p1 + k; }
    else { const int k2 = k - n1 * BK; a0 = a2p0 + k2; a1 = a2p1 + k2; }
    gload16(a0, Ab);
    gload16(a1, Ab + 4096);
    gload16(wp0 + k, Bb);
    gload16(wp1 + k, Bb + 4096);
    gload16(wp2 + k, Bb + 8192);
    gload16(wp3 + k, Bb + 12288);
  };

  const int swz  = fr & 7;
  const int co0  = ((fq) ^ swz) * 16;
  const int co1  = ((4 + fq) ^ swz) * 16;
  const int arow0 = (wm * 32 + fr) * 128;
  const int arow1 = (wm * 32 + 16 + fr) * 128;
  const int brow  = (wn * 64 + fr) * 128;

  auto compute = [&](int bf) {
    const char* Ab = ldsbase + bf * BUFB;
    const char* Bb = Ab + 8192;
#pragma unroll
    for (int kk = 0; kk < 2; ++kk) {
      const int co = kk ? co1 : co0;
      bf16x8 av0 = *(const bf16x8*)(Ab + arow0 + co);
      bf16x8 av1 = *(const bf16x8*)(Ab + arow1 + co);
      bf16x8 bv[4];
#pragma unroll
      for (int j = 0; j < 4; ++j)
        bv[j] = *(const bf16x8*)(Bb + brow + j * 2048 + co);
#pragma unroll
      for (int j = 0; j < 4; ++j) {
        acc[0][j] = __builtin_amdgcn_mfma_f32_16x16x32_bf16(av0, bv[j], acc[0][j], 0, 0, 0);
        acc[1][j] = __builtin_amdgcn_mfma_f32_16x16x32_bf16(av1, bv[j], acc[1][j], 0, 0, 0);
      }
    }
  };

  stage(0, 0);
  if (nTot > 1) stage(1, 1);
  int cb = 0, sb = 2;
  for (int it = 0; it < nTot; ++it) {
    if (it == nTot - 1) {
      asm volatile("s_waitcnt vmcnt(0)" ::: "memory");
    } else {
      asm volatile("s_waitcnt vmcnt(6)" ::: "memory");
    }
    __builtin_amdgcn_s_barrier();
    if (it + 2 < nTot) stage(it + 2, sb);
    sb = (sb == 2) ? 0 : sb + 1;
    compute(cb);
    cb = (cb == 2) ? 0 : cb + 1;
  }
  __syncthreads();

  if (EPI == 1) {
#pragma unroll
    for (int i = 0; i < 2; ++i)
#pragma unroll
      for (int j = 0; j < 4; ++j)
#pragma unroll
        for (int v = 0; v < 4; ++v) {
          int row = wm * 32 + i * 16 + fq * 4 + v;
          int col = wn * 64 + j * 16 + fr;
          sm.gate[row * 129 + col] = acc[i][j][v] + bias4[j];
        }
    __syncthreads();
    const int u0 = n0 >> 2;
#pragma unroll
    for (int itc = 0; itc < 8; ++itc) {
      int ci = itc * 256 + t;
      int brw = ci >> 5;
      int ju  = ci & 31;
      const float* gp = &sm.gate[brw * 129 + ju * 4];
      float iv = fsigmoid(gp[0]);
      float fv = fsigmoid(gp[1]);
      float gv = ftanh(gp[2]);
      float ov = fsigmoid(gp[3]);
      size_t cix = (size_t)(m0 + brw) * H_SZ + (u0 + ju);
      float cn = fv * cbuf[cix] + iv * gv;
      cbuf[cix] = cn;
      hout[cix] = (bf16_t)(ov * ftanh(cn));
    }
  }

  if (EPI == 2) {
#pragma unroll
    for (int i = 0; i < 2; ++i)
#pragma unroll
      for (int j = 0; j < 4; ++j)
#pragma unroll
        for (int v = 0; v < 4; ++v) {
          int gr = m0 + wm * 32 + i * 16 + fq * 4 + v;
          int gc = n0 + wn * 64 + j * 16 + fr;
          int orig = (gr & 3) * H_SZ + (gr >> 2);
          float val = acc[i][j][v] + addm[(size_t)orig * H_SZ + gc];
          outb[(size_t)gr * H_SZ + gc] = (bf16_t)val;
        }
  }

  if (EPI == 3) {
#pragma unroll
    for (int i = 0; i < 2; ++i)
#pragma unroll
      for (int j = 0; j < 4; ++j)
#pragma unroll
        for (int v = 0; v < 4; ++v) {
          int m = m0 + wm * 32 + i * 16 + fq * 4 + v;
          int n = n0 + wn * 64 + j * 16 + fr;
          if (n < D_SZ) {
            int ts = m >> 9;
            int bb = m & 511;
            outf[((size_t)bb * TMAX + ts) * D_SZ + n] = acc[i][j][v] + bias4[j];
          }
        }
  }
}

// src (B,S,D) fp32 -> srcbf (S,B,DP) bf16, zero-padded d>=216
__global__ void k_convert_src(const float* __restrict__ src, bf16_t* __restrict__ dst) {
  int idx = blockIdx.x * 256 + threadIdx.x;
  int total = S_SZ * B_SZ * DP;
  if (idx >= total) return;
  int d = idx % DP;
  int r = idx / DP;
  int b = r % B_SZ;
  int tt = r / B_SZ;
  float v = (d < D_SZ) ? src[((size_t)b * S_SZ + tt) * D_SZ + d] : 0.f;
  dst[idx] = (bf16_t)v;
}

__global__ void k_build_wcat(const float* __restrict__ Wih, const float* __restrict__ Whh,
                             bf16_t* __restrict__ Wcat) {
  int idx = blockIdx.x * 256 + threadIdx.x;
  if (idx >= NG * KENC) return;
  int k = idx % KENC;
  int r = idx / KENC;
  int o = (r & 3) * H_SZ + (r >> 2);
  float v;
  if (k < D_SZ)      v = Wih[(size_t)o * D_SZ + k];
  else if (k < DP)   v = 0.f;
  else               v = Whh[(size_t)o * H_SZ + (k - DP)];
  Wcat[idx] = (bf16_t)v;
}

__global__ void k_build_wout(const float* __restrict__ Wout, bf16_t* __restrict__ WoutB,
                             bf16_t* __restrict__ WoutT) {
  int idx = blockIdx.x * 256 + threadIdx.x;
  if (idx < 256 * H_SZ) {
    int h = idx % H_SZ, d = idx / H_SZ;
    WoutB[idx] = (bf16_t)((d < D_SZ) ? Wout[(size_t)d * H_SZ + h] : 0.f);
  }
  if (idx < H_SZ * DP) {
    int d = idx % DP, h = idx / DP;
    WoutT[idx] = (bf16_t)((d < D_SZ) ? Wout[(size_t)d * H_SZ + h] : 0.f);
  }
}

__global__ void k_build_bias(const float* __restrict__ bih, const float* __restrict__ bhh,
                             const float* __restrict__ Wih, const float* __restrict__ bout,
                             float* __restrict__ biasE, float* __restrict__ biasD) {
  int r = blockIdx.x * 256 + threadIdx.x;
  if (r >= NG) return;
  int o = (r & 3) * H_SZ + (r >> 2);
  float be = bih[o] + bhh[o];
  biasE[r] = be;
  float s = 0.f;
  const float* wr = Wih + (size_t)o * D_SZ;
  for (int d = 0; d < D_SZ; ++d) s += wr[d] * bout[d];
  biasD[r] = be + s;
}

extern "C" void kernel_launch(void* const* d_in, const int* in_sizes, int n_in,
                              void* d_out, int out_size, void* d_ws, size_t ws_size,
                              hipStream_t stream) {
  const float* src  = (const float*)d_in[0];
  const float* Wih  = (const float*)d_in[1];
  const float* Whh  = (const float*)d_in[2];
  const float* bih  = (const float*)d_in[3];
  const float* bhh  = (const float*)d_in[4];
  const float* Wout = (const float*)d_in[5];
  const float* bout = (const float*)d_in[6];

  char* ws = (char*)d_ws;
  size_t off = 0;
  auto alloc = [&](size_t bytes) {
    void* p = ws + off;
    off = (off + bytes + 255) & ~(size_t)255;
    return p;
  };
  bf16_t* srcbf = (bf16_t*)alloc((size_t)S_SZ * B_SZ * DP * 2);
  bf16_t* Wcat  = (bf16_t*)alloc((size_t)NG * KENC * 2);
  bf16_t* Wdec  = (bf16_t*)alloc((size_t)NG * H_SZ * 2);
  bf16_t* WoutB = (bf16_t*)alloc((size_t)256 * H_SZ * 2);
  bf16_t* WoutT = (bf16_t*)alloc((size_t)H_SZ * DP * 2);
  float*  biasE = (float*)alloc((size_t)NG * 4);
  float*  biasD = (float*)alloc((size_t)NG * 4);
  float*  cbuf  = (float*)alloc((size_t)B_SZ * H_SZ * 4);
  bf16_t* hP0   = (bf16_t*)alloc((size_t)B_SZ * H_SZ * 2);
  bf16_t* hP1   = (bf16_t*)alloc((size_t)B_SZ * H_SZ * 2);
  bf16_t* Hs    = (bf16_t*)alloc((size_t)TMAX * B_SZ * H_SZ * 2);
  unsigned* flags = (unsigned*)alloc(1024);

  hipMemsetAsync(hP0, 0, (size_t)B_SZ * H_SZ * 2, stream);
  hipMemsetAsync(flags, 0, 1024, stream);

  k_convert_src<<<(S_SZ * B_SZ * DP + 255) / 256, 256, 0, stream>>>(src, srcbf);
  k_build_wcat<<<(NG * KENC + 255) / 256, 256, 0, stream>>>(Wih, Whh, Wcat);
  k_build_wout<<<1024, 256, 0, stream>>>(Wout, WoutB, WoutT);
  k_build_bias<<<(NG + 255) / 256, 256, 0, stream>>>(bih, bhh, Wih, bout, biasE, biasD);

  // W_dec = W_hh(reordered) + W_ih(reordered) @ W_out   (M=4096, N=1024, K=256)
  gemm_step<2><<<dim3(H_SZ / BN, NG / BM), 256, 0, stream>>>(
      Wcat, KENC, DP / BK, nullptr, 0, 0, WoutT, DP,
      nullptr, nullptr, nullptr, Whh, Wdec, nullptr);

  // All 144 sequential steps: one persistent cooperative kernel, 512 threads.
  {
    const bf16_t* a_src = srcbf;
    const bf16_t* a_wc  = Wcat;
    const bf16_t* a_wd  = Wdec;
    const float*  a_bE  = biasE;
    const float*  a_bD  = biasD;
    bf16_t*       a_hA  = hP0;
    bf16_t*       a_hB  = hP1;
    bf16_t*       a_Hs  = Hs;
    unsigned*     a_fl  = flags;
    void* kargs[] = {&a_src, &a_wc, &a_wd, &a_bE, &a_bD,
                     &a_hA, &a_hB, &a_Hs, &a_fl};
    hipLaunchCooperativeKernel((void*)lstm_chain, dim3(256), dim3(512),
                               kargs, 0, stream);
  }

  // Final projection: Y(12288 x 216) = Hs(12288 x 1024) @ W_out^T + b_out
  gemm_step<3><<<dim3(2, (TMAX * B_SZ) / BM), 256, 0, stream>>>(
      nullptr, 0, 0, Hs, H_SZ, H_SZ / BK, WoutB, H_SZ,
      bout, nullptr, nullptr, nullptr, nullptr, (float*)d_out);
}